// Round 3
// baseline (237.844 us; speedup 1.0000x reference)
//
#include <hip/hip_runtime.h>
#include <hip/hip_bf16.h>

// BCNet fused pipeline, MI355X gfx950 — round 3: 256² counted-vmcnt pipeline for the big GEMMs.
//   C0: convert v,q,Wv,Wq,W2 f32 -> bf16 (ws)
//   K1: q_[1792,2048]   = relu(qb @ Wqb^T + bq)                  (128² m97 kernel)
//   K2: qw[128,2048]    = sum_q q_[b*14+q,:] * wh[q]
//   K3: logits[4608,2048] = relu(vb @ Wvb^T + bv) * qw + bh      (256² pipelined)
//   K4: out[4608,2048]  = logits @ W2b^T + b2                    (256² pipelined)

typedef __attribute__((ext_vector_type(4))) float f32x4;
typedef __attribute__((ext_vector_type(8))) short short8;

__device__ __forceinline__ short f2bf(float f) {
    union { float f; unsigned u; } x; x.f = f;
    unsigned u = x.u;
    unsigned r = (u + 0x7FFFu + ((u >> 16) & 1u)) >> 16;   // RN-even
    return (short)(r & 0xFFFFu);
}
__device__ __forceinline__ float bf2f(short s) {
    union { unsigned u; float f; } x; x.u = ((unsigned)(unsigned short)s) << 16;
    return x.f;
}

__device__ __forceinline__ void gload_lds16(const short* g, short* l) {
    __builtin_amdgcn_global_load_lds(
        (const __attribute__((address_space(1))) unsigned int*)g,
        (__attribute__((address_space(3))) unsigned int*)l,
        16, 0, 0);
}

// ---------------- f32 -> bf16 conversion ----------------
__global__ __launch_bounds__(256)
void cvt_bf16(const float* __restrict__ in, short* __restrict__ out, int n)
{
    const int stride = gridDim.x * 256 * 8;
    for (int i = (blockIdx.x * 256 + threadIdx.x) * 8; i < n; i += stride) {
        f32x4 a = *(const f32x4*)&in[i];
        f32x4 b = *(const f32x4*)&in[i + 4];
        short8 s;
        #pragma unroll
        for (int j = 0; j < 4; ++j) { s[j] = f2bf(a[j]); s[4 + j] = f2bf(b[j]); }
        *(short8*)&out[i] = s;
    }
}

// ---------------- 128² m97-structure GEMM (used for K1) ----------------
// C[M,N] = A[M,K] * B[N,K]^T, bf16 in; EPI 0 = relu(acc+bias[n]) -> bf16
__global__ __launch_bounds__(256)
void gemm_bt128(const short* __restrict__ Ab, const short* __restrict__ Bb,
                const float* __restrict__ bias, void* __restrict__ Cp,
                int M, int N, int K)
{
    __shared__ short ldsA[128 * 32];
    __shared__ short ldsB[128 * 32];

    const int tid    = threadIdx.x;
    const int lane   = tid & 63;
    const int wid    = tid >> 6;
    const int wr     = wid >> 1;
    const int wc     = wid & 1;
    const int lrow   = lane & 15;
    const int lchunk = lane >> 4;

    const int row0 = blockIdx.x * 128;
    const int col0 = blockIdx.y * 128;

    const int s_r = (lane >> 2);
    const int s_c = (lane & 3) * 8;

    f32x4 acc[4][4];
    #pragma unroll
    for (int i = 0; i < 4; ++i)
        #pragma unroll
        for (int j = 0; j < 4; ++j)
            acc[i][j] = (f32x4)0.0f;

    const int nk = K >> 5;

    for (int kt = 0; kt < nk; ++kt) {
        const int kc = kt * 32;
        if (kt) __syncthreads();
        #pragma unroll
        for (int i = 0; i < 2; ++i) {
            const int r = wid * 32 + i * 16 + s_r;
            gload_lds16(&Ab[(size_t)(row0 + r) * K + kc + s_c], &ldsA[wid * 1024 + i * 512]);
            gload_lds16(&Bb[(size_t)(col0 + r) * K + kc + s_c], &ldsB[wid * 1024 + i * 512]);
        }
        __syncthreads();

        short8 af[4], bfv[4];
        #pragma unroll
        for (int mi = 0; mi < 4; ++mi)
            af[mi] = *(const short8*)&ldsA[(wr * 64 + mi * 16 + lrow) * 32 + lchunk * 8];
        #pragma unroll
        for (int ni = 0; ni < 4; ++ni)
            bfv[ni] = *(const short8*)&ldsB[(wc * 64 + ni * 16 + lrow) * 32 + lchunk * 8];
        #pragma unroll
        for (int mi = 0; mi < 4; ++mi)
            #pragma unroll
            for (int ni = 0; ni < 4; ++ni)
                acc[mi][ni] = __builtin_amdgcn_mfma_f32_16x16x32_bf16(af[mi], bfv[ni], acc[mi][ni], 0, 0, 0);
    }

    #pragma unroll
    for (int mi = 0; mi < 4; ++mi)
        #pragma unroll
        for (int ni = 0; ni < 4; ++ni)
            #pragma unroll
            for (int r = 0; r < 4; ++r) {
                const int row = row0 + wr * 64 + mi * 16 + lchunk * 4 + r;
                const int col = col0 + wc * 64 + ni * 16 + lrow;
                float val = fmaxf(acc[mi][ni][r] + bias[col], 0.0f);
                ((short*)Cp)[(size_t)row * N + col] = f2bf(val);
            }
}

// ---------------- 256² counted-vmcnt pipelined GEMM (K3/K4) ----------------
// C[M,N] = A[M,K] * B[N,K]^T.
// EPI: 1 = relu(acc+bias[n]) * qw[row/36, n] + bh -> bf16
//      2 = acc + bias[n]                          -> f32
// 8 waves (2M x 4N), per-wave output 128x64, BK=64, double-buffered 128KB LDS.
// Staging: linear LDS dest via global_load_lds + pre-swizzled global source;
// reads XOR-swizzled (byte ^= (row&7)<<4) -> no 16-way ds_read conflicts.
// Per K-tile: 4 quadrant phases; one counted s_waitcnt vmcnt(2) per tile.
template<int EPI>
__global__ __launch_bounds__(512, 2)
void gemm256(const short* __restrict__ Ab, const short* __restrict__ Bb,
             const float* __restrict__ bias, const float* __restrict__ qw,
             const float* __restrict__ bh_p, void* __restrict__ Cp,
             int M, int N, int K)
{
    __shared__ short ldsA[2][256 * 64];   // 64 KB
    __shared__ short ldsB[2][256 * 64];   // 64 KB

    const int tid  = threadIdx.x;
    const int lane = tid & 63;
    const int w    = tid >> 6;     // 0..7
    const int wr   = w >> 2;       // 0..1  (128-row block)
    const int wc   = w & 3;        // 0..3  (64-col block)
    const int fr   = lane & 15;    // fragment row
    const int fc   = lane >> 4;    // k-chunk 0..3

    const int row0 = blockIdx.x * 256;
    const int col0 = blockIdx.y * 256;

    const int sl_r = lane >> 3;                    // 0..7: row within an 8-row slice
    const int sl_c = ((lane & 7) ^ sl_r) * 8;      // pre-swizzled source col (elems)

    const int nt = K >> 6;

    f32x4 acc[8][4];
    #pragma unroll
    for (int i = 0; i < 8; ++i)
        #pragma unroll
        for (int j = 0; j < 4; ++j)
            acc[i][j] = (f32x4)0.0f;

    // stage half h (128 rows) of tile t's A (or B) panel: 2 x global_load_lds / thread
    auto stageA = [&](int t, int h) {
        const int kc = t * 64;
        short* dst = &ldsA[t & 1][(h * 128 + w * 16) * 64];
        const short* src = &Ab[(size_t)(row0 + h * 128 + w * 16 + sl_r) * K + kc + sl_c];
        gload_lds16(src, dst);
        gload_lds16(src + 8 * (size_t)K, dst + 8 * 64);
    };
    auto stageB = [&](int t, int h) {
        const int kc = t * 64;
        short* dst = &ldsB[t & 1][(h * 128 + w * 16) * 64];
        const short* src = &Bb[(size_t)(col0 + h * 128 + w * 16 + sl_r) * K + kc + sl_c];
        gload_lds16(src, dst);
        gload_lds16(src + 8 * (size_t)K, dst + 8 * 64);
    };

    // swizzled fragment reads
    auto rdA = [&](int t, int mi, int ks) -> short8 {
        const int row = wr * 128 + mi * 16 + fr;
        const int off = row * 128 + ((ks * 64 + fc * 16) ^ ((row & 7) << 4));
        return *(const short8*)((const char*)&ldsA[t & 1][0] + off);
    };
    auto rdB = [&](int t, int ni, int ks) -> short8 {
        const int row = wc * 64 + ni * 16 + fr;
        const int off = row * 128 + ((ks * 64 + fc * 16) ^ ((row & 7) << 4));
        return *(const short8*)((const char*)&ldsB[t & 1][0] + off);
    };

    // ---- prologue: tile 0 fully + tile 1 Ah0 in flight
    stageA(0, 0); stageA(0, 1); stageB(0, 0); stageB(0, 1);
    if (nt > 1) {
        stageA(1, 0);
        asm volatile("s_waitcnt vmcnt(2)" ::: "memory");
    } else {
        asm volatile("s_waitcnt vmcnt(0)" ::: "memory");
    }
    __builtin_amdgcn_s_barrier();

    short8 a8[8];   // current A half-block frags: 4 mi x 2 ks
    short8 b8[8];   // full B-tile frags:          4 ni x 2 ks

    for (int t = 0; t < nt; ++t) {
        // ---- Q0: stage (t+1).Ah1 | read A(mh0)+B(nh0) | MFMA (mh0,nh0)
        if (t + 1 < nt) stageA(t + 1, 1);
        #pragma unroll
        for (int m = 0; m < 4; ++m)
            #pragma unroll
            for (int ks = 0; ks < 2; ++ks) a8[m * 2 + ks] = rdA(t, m, ks);
        #pragma unroll
        for (int n = 0; n < 2; ++n)
            #pragma unroll
            for (int ks = 0; ks < 2; ++ks) b8[n * 2 + ks] = rdB(t, n, ks);
        __builtin_amdgcn_s_barrier();
        __builtin_amdgcn_s_setprio(1);
        #pragma unroll
        for (int m = 0; m < 4; ++m)
            #pragma unroll
            for (int n = 0; n < 2; ++n)
                #pragma unroll
                for (int ks = 0; ks < 2; ++ks)
                    acc[m][n] = __builtin_amdgcn_mfma_f32_16x16x32_bf16(a8[m * 2 + ks], b8[n * 2 + ks], acc[m][n], 0, 0, 0);
        __builtin_amdgcn_s_setprio(0);
        __builtin_amdgcn_s_barrier();

        // ---- Q1: stage (t+1).Bh0 | read B(nh1) | MFMA (mh0,nh1)
        if (t + 1 < nt) stageB(t + 1, 0);
        #pragma unroll
        for (int n = 0; n < 2; ++n)
            #pragma unroll
            for (int ks = 0; ks < 2; ++ks) b8[4 + n * 2 + ks] = rdB(t, 2 + n, ks);
        __builtin_amdgcn_s_barrier();
        __builtin_amdgcn_s_setprio(1);
        #pragma unroll
        for (int m = 0; m < 4; ++m)
            #pragma unroll
            for (int n = 0; n < 2; ++n)
                #pragma unroll
                for (int ks = 0; ks < 2; ++ks)
                    acc[m][2 + n] = __builtin_amdgcn_mfma_f32_16x16x32_bf16(a8[m * 2 + ks], b8[4 + n * 2 + ks], acc[m][2 + n], 0, 0, 0);
        __builtin_amdgcn_s_setprio(0);
        __builtin_amdgcn_s_barrier();

        // ---- Q2: stage (t+1).Bh1 | read A(mh1) | MFMA (mh1,nh1)
        if (t + 1 < nt) stageB(t + 1, 1);
        #pragma unroll
        for (int m = 0; m < 4; ++m)
            #pragma unroll
            for (int ks = 0; ks < 2; ++ks) a8[m * 2 + ks] = rdA(t, 4 + m, ks);
        __builtin_amdgcn_s_barrier();
        __builtin_amdgcn_s_setprio(1);
        #pragma unroll
        for (int m = 0; m < 4; ++m)
            #pragma unroll
            for (int n = 0; n < 2; ++n)
                #pragma unroll
                for (int ks = 0; ks < 2; ++ks)
                    acc[4 + m][2 + n] = __builtin_amdgcn_mfma_f32_16x16x32_bf16(a8[m * 2 + ks], b8[4 + n * 2 + ks], acc[4 + m][2 + n], 0, 0, 0);
        __builtin_amdgcn_s_setprio(0);
        __builtin_amdgcn_s_barrier();

        // ---- Q3: stage (t+2).Ah0 | MFMA (mh1,nh0) (B nh0 frags still live)
        if (t + 2 < nt) stageA(t + 2, 0);
        __builtin_amdgcn_s_barrier();
        __builtin_amdgcn_s_setprio(1);
        #pragma unroll
        for (int m = 0; m < 4; ++m)
            #pragma unroll
            for (int n = 0; n < 2; ++n)
                #pragma unroll
                for (int ks = 0; ks < 2; ++ks)
                    acc[4 + m][n] = __builtin_amdgcn_mfma_f32_16x16x32_bf16(a8[m * 2 + ks], b8[n * 2 + ks], acc[4 + m][n], 0, 0, 0);
        __builtin_amdgcn_s_setprio(0);
        // drain: everything except the (t+2).Ah0 just issued must have arrived
        if (t + 2 < nt) { asm volatile("s_waitcnt vmcnt(2)" ::: "memory"); }
        else            { asm volatile("s_waitcnt vmcnt(0)" ::: "memory"); }
        __builtin_amdgcn_s_barrier();
    }

    // ---- epilogue: C/D layout col = lane&15, row = (lane>>4)*4 + reg
    const float bhv = (EPI == 1) ? bh_p[0] : 0.0f;
    #pragma unroll
    for (int m = 0; m < 8; ++m) {
        #pragma unroll
        for (int n = 0; n < 4; ++n) {
            #pragma unroll
            for (int r = 0; r < 4; ++r) {
                const int row = row0 + wr * 128 + m * 16 + fc * 4 + r;
                const int col = col0 + wc * 64 + n * 16 + fr;
                float val = acc[m][n][r];
                if (EPI == 1) {
                    val = fmaxf(val + bias[col], 0.0f);
                    const int b = row / 36;
                    val = val * qw[b * 2048 + col] + bhv;
                    ((short*)Cp)[(size_t)row * N + col] = f2bf(val);
                } else {
                    ((float*)Cp)[(size_t)row * N + col] = val + bias[col];
                }
            }
        }
    }
}

// qw[b,h] = sum_q bf2f(q_[b*14+q, h]) * wh[q]
__global__ __launch_bounds__(256)
void qw_reduce(const short* __restrict__ q_, const float* __restrict__ wh,
               float* __restrict__ qw)
{
    const int idx = blockIdx.x * 256 + threadIdx.x;
    const int b = idx >> 11;
    const int h = idx & 2047;
    float s = 0.0f;
    #pragma unroll
    for (int qq = 0; qq < 14; ++qq)
        s += bf2f(q_[(size_t)(b * 14 + qq) * 2048 + h]) * wh[qq];
    qw[idx] = s;
}

extern "C" void kernel_launch(void* const* d_in, const int* in_sizes, int n_in,
                              void* d_out, int out_size, void* d_ws, size_t ws_size,
                              hipStream_t stream)
{
    const float* v  = (const float*)d_in[0];
    const float* q  = (const float*)d_in[1];
    const float* Wv = (const float*)d_in[2];
    const float* bv = (const float*)d_in[3];
    const float* Wq = (const float*)d_in[4];
    const float* bq = (const float*)d_in[5];
    const float* wh = (const float*)d_in[6];
    const float* bh = (const float*)d_in[7];
    const float* W2 = (const float*)d_in[8];
    const float* b2 = (const float*)d_in[9];
    float* out = (float*)d_out;

    char* ws = (char*)d_ws;
    short* vb     = (short*)(ws);                  // 4608*2048*2 = 18,874,368
    short* Wvb    = (short*)(ws + 18874368);       // 2048*2048*2 =  8,388,608
    short* W2b    = (short*)(ws + 27262976);       // 2048*2048*2 =  8,388,608
    short* qb     = (short*)(ws + 35651584);       // 1792*1024*2 =  3,670,016
    short* Wqb    = (short*)(ws + 39321600);       // 2048*1024*2 =  4,194,304
    short* q_ws   = (short*)(ws + 43515904);       // 1792*2048*2 =  7,340,032
    float* qw     = (float*)(ws + 50855936);       // 128*2048*4  =  1,048,576
    short* logits = (short*)(ws + 51904512);       // 4608*2048*2 = 18,874,368
    // total: 70,778,880 B

    auto cvt = [&](const float* src, short* dst, int n) {
        int blocks = (n / 8 + 255) / 256;
        if (blocks > 2048) blocks = 2048;
        cvt_bf16<<<blocks, 256, 0, stream>>>(src, dst, n);
    };

    cvt(q,  qb,  1792 * 1024);
    cvt(Wq, Wqb, 2048 * 1024);
    cvt(v,  vb,  4608 * 2048);
    cvt(Wv, Wvb, 2048 * 2048);
    cvt(W2, W2b, 2048 * 2048);

    // K1: q_ = relu(qb @ Wqb^T + bq)   M=1792, N=2048, K=1024  (128² kernel)
    gemm_bt128<<<dim3(1792 / 128, 2048 / 128), 256, 0, stream>>>(
        qb, Wqb, bq, q_ws, 1792, 2048, 1024);

    // K2: qw reduce
    qw_reduce<<<(128 * 2048) / 256, 256, 0, stream>>>(q_ws, wh, qw);

    // K3: logits = relu(vb @ Wvb^T + bv) * qw + bh   M=4608, N=2048, K=2048
    gemm256<1><<<dim3(4608 / 256, 2048 / 256), 512, 0, stream>>>(
        vb, Wvb, bv, qw, bh, logits, 4608, 2048, 2048);

    // K4: out = logits @ W2b^T + b2   M=4608, N=2048, K=2048
    gemm256<2><<<dim3(4608 / 256, 2048 / 256), 512, 0, stream>>>(
        logits, W2b, b2, nullptr, nullptr, out, 4608, 2048, 2048);
}

// Round 4
// 192.569 us; speedup vs baseline: 1.2351x; 1.2351x over previous
//
#include <hip/hip_runtime.h>
#include <hip/hip_bf16.h>

// BCNet fused pipeline, MI355X gfx950 — round 4: quadrant-cooperative 256² pipeline,
// deep prefetch (stage 2 tiles ahead), counted-vmcnt drains 6-7 phases after issue.
//   C0: convert v,q,Wv,Wq,W2 f32 -> bf16 (ws)
//   K1: q_[1792,2048]   = relu(qb @ Wqb^T + bq)                  (128² m97 kernel)
//   K2: qw[128,2048]    = sum_q q_[b*14+q,:] * wh[q]
//   K3: logits[4608,2048] = relu(vb @ Wvb^T + bv) * qw + bh      (256² pipelined)
//   K4: out[4608,2048]  = logits @ W2b^T + b2                    (256² pipelined)

typedef __attribute__((ext_vector_type(4))) float f32x4;
typedef __attribute__((ext_vector_type(8))) short short8;

__device__ __forceinline__ short f2bf(float f) {
    union { float f; unsigned u; } x; x.f = f;
    unsigned u = x.u;
    unsigned r = (u + 0x7FFFu + ((u >> 16) & 1u)) >> 16;   // RN-even
    return (short)(r & 0xFFFFu);
}
__device__ __forceinline__ float bf2f(short s) {
    union { unsigned u; float f; } x; x.u = ((unsigned)(unsigned short)s) << 16;
    return x.f;
}

__device__ __forceinline__ void gload_lds16(const short* g, short* l) {
    __builtin_amdgcn_global_load_lds(
        (const __attribute__((address_space(1))) unsigned int*)g,
        (__attribute__((address_space(3))) unsigned int*)l,
        16, 0, 0);
}

// ---------------- f32 -> bf16 conversion ----------------
__global__ __launch_bounds__(256)
void cvt_bf16(const float* __restrict__ in, short* __restrict__ out, int n)
{
    const int stride = gridDim.x * 256 * 8;
    for (int i = (blockIdx.x * 256 + threadIdx.x) * 8; i < n; i += stride) {
        f32x4 a = *(const f32x4*)&in[i];
        f32x4 b = *(const f32x4*)&in[i + 4];
        short8 s;
        #pragma unroll
        for (int j = 0; j < 4; ++j) { s[j] = f2bf(a[j]); s[4 + j] = f2bf(b[j]); }
        *(short8*)&out[i] = s;
    }
}

// ---------------- 128² m97-structure GEMM (K1) ----------------
__global__ __launch_bounds__(256)
void gemm_bt128(const short* __restrict__ Ab, const short* __restrict__ Bb,
                const float* __restrict__ bias, void* __restrict__ Cp,
                int M, int N, int K)
{
    __shared__ short ldsA[128 * 32];
    __shared__ short ldsB[128 * 32];

    const int tid    = threadIdx.x;
    const int lane   = tid & 63;
    const int wid    = tid >> 6;
    const int wr     = wid >> 1;
    const int wc     = wid & 1;
    const int lrow   = lane & 15;
    const int lchunk = lane >> 4;

    const int row0 = blockIdx.x * 128;
    const int col0 = blockIdx.y * 128;

    const int s_r = (lane >> 2);
    const int s_c = (lane & 3) * 8;

    f32x4 acc[4][4];
    #pragma unroll
    for (int i = 0; i < 4; ++i)
        #pragma unroll
        for (int j = 0; j < 4; ++j)
            acc[i][j] = (f32x4)0.0f;

    const int nk = K >> 5;

    for (int kt = 0; kt < nk; ++kt) {
        const int kc = kt * 32;
        if (kt) __syncthreads();
        #pragma unroll
        for (int i = 0; i < 2; ++i) {
            const int r = wid * 32 + i * 16 + s_r;
            gload_lds16(&Ab[(size_t)(row0 + r) * K + kc + s_c], &ldsA[wid * 1024 + i * 512]);
            gload_lds16(&Bb[(size_t)(col0 + r) * K + kc + s_c], &ldsB[wid * 1024 + i * 512]);
        }
        __syncthreads();

        short8 af[4], bfv[4];
        #pragma unroll
        for (int mi = 0; mi < 4; ++mi)
            af[mi] = *(const short8*)&ldsA[(wr * 64 + mi * 16 + lrow) * 32 + lchunk * 8];
        #pragma unroll
        for (int ni = 0; ni < 4; ++ni)
            bfv[ni] = *(const short8*)&ldsB[(wc * 64 + ni * 16 + lrow) * 32 + lchunk * 8];
        #pragma unroll
        for (int mi = 0; mi < 4; ++mi)
            #pragma unroll
            for (int ni = 0; ni < 4; ++ni)
                acc[mi][ni] = __builtin_amdgcn_mfma_f32_16x16x32_bf16(af[mi], bfv[ni], acc[mi][ni], 0, 0, 0);
    }

    #pragma unroll
    for (int mi = 0; mi < 4; ++mi)
        #pragma unroll
        for (int ni = 0; ni < 4; ++ni)
            #pragma unroll
            for (int r = 0; r < 4; ++r) {
                const int row = row0 + wr * 64 + mi * 16 + lchunk * 4 + r;
                const int col = col0 + wc * 64 + ni * 16 + lrow;
                float val = fmaxf(acc[mi][ni][r] + bias[col], 0.0f);
                ((short*)Cp)[(size_t)row * N + col] = f2bf(val);
            }
}

// ---------------- 256² quadrant-cooperative pipelined GEMM (K3/K4) ----------------
// C[M,N] = A[M,K] * B[N,K]^T, bf16 in.
// EPI: 1 = relu(acc+bias[n]) * qw[row/36, n] + bh -> bf16
//      2 = acc + bias[n]                          -> f32
// 8 waves all cooperate on one 128x128 C-quadrant per phase (wave piece 64x32).
// Quadrant order per K-tile: (0,0) (0,1) (1,1) (1,0) -> A/B register reuse.
// Each phase reads exactly one A-half or B-half -> half-regions freed after one
// phase and restaged 2 K-tiles ahead (7-phase prefetch). Drains target loads
// issued 6-7 phases earlier (counted vmcnt; never 0 in steady state).
template<int EPI>
__global__ __launch_bounds__(512, 2)
void gemm256(const short* __restrict__ Ab, const short* __restrict__ Bb,
             const float* __restrict__ bias, const float* __restrict__ qw,
             const float* __restrict__ bh_p, void* __restrict__ Cp,
             int M, int N, int K)
{
    __shared__ short ldsA[2][256 * 64];   // 64 KB
    __shared__ short ldsB[2][256 * 64];   // 64 KB

    const int tid  = threadIdx.x;
    const int lane = tid & 63;
    const int w    = tid >> 6;     // 0..7
    const int swr  = w >> 2;       // 0..1: 64-row piece within a quadrant
    const int swc  = w & 3;        // 0..3: 32-col piece within a quadrant
    const int fr   = lane & 15;
    const int fc   = lane >> 4;

    const int row0 = blockIdx.x * 256;
    const int col0 = blockIdx.y * 256;

    const int sl_r = lane >> 3;                    // 0..7
    const int sl_c = ((lane & 7) ^ sl_r) * 8;      // pre-swizzled source col

    const int nt = K >> 6;        // assumes nt >= 3 (here 16 or 32)

    f32x4 acc[2][2][4][2];        // [qm][qn][m][n]
    #pragma unroll
    for (int qm = 0; qm < 2; ++qm)
        #pragma unroll
        for (int qn = 0; qn < 2; ++qn)
            #pragma unroll
            for (int m = 0; m < 4; ++m)
                #pragma unroll
                for (int n = 0; n < 2; ++n)
                    acc[qm][qn][m][n] = (f32x4)0.0f;

    auto stageA = [&](int t, int h) {
        short* dst = &ldsA[t & 1][(h * 128 + w * 16) * 64];
        const short* src = &Ab[(size_t)(row0 + h * 128 + w * 16 + sl_r) * K + t * 64 + sl_c];
        gload_lds16(src, dst);
        gload_lds16(src + (size_t)8 * K, dst + 8 * 64);
    };
    auto stageB = [&](int t, int h) {
        short* dst = &ldsB[t & 1][(h * 128 + w * 16) * 64];
        const short* src = &Bb[(size_t)(col0 + h * 128 + w * 16 + sl_r) * K + t * 64 + sl_c];
        gload_lds16(src, dst);
        gload_lds16(src + (size_t)8 * K, dst + 8 * 64);
    };

    auto rdA = [&](int t, int qm, int m, int ks) -> short8 {
        const int row = qm * 128 + swr * 64 + m * 16 + fr;
        return *(const short8*)((const char*)&ldsA[t & 1][0] +
               row * 128 + ((ks * 64 + fc * 16) ^ ((row & 7) << 4)));
    };
    auto rdB = [&](int t, int qn, int n, int ks) -> short8 {
        const int row = qn * 128 + swc * 32 + n * 16 + fr;
        return *(const short8*)((const char*)&ldsB[t & 1][0] +
               row * 128 + ((ks * 64 + fc * 16) ^ ((row & 7) << 4)));
    };

    short8 aF[4][2], bF0[2][2], bF1[2][2];

    // prologue: tiles 0,1 in per-tile issue order [Ah0, Bh0, Bh1, Ah1] (16 loads)
    stageA(0, 0); stageB(0, 0); stageB(0, 1); stageA(0, 1);
    stageA(1, 0); stageB(1, 0); stageB(1, 1); stageA(1, 1);
    asm volatile("s_waitcnt vmcnt(12)" ::: "memory");   // Ah0(0)+Bh0(0) arrived
    __builtin_amdgcn_s_barrier();

#define BAR()   __builtin_amdgcn_s_barrier()
#define PRIO1() __builtin_amdgcn_s_setprio(1)
#define PRIO0() __builtin_amdgcn_s_setprio(0)

#define MFMA_Q(QM, QN, BF)                                                     \
    _Pragma("unroll") for (int m_ = 0; m_ < 4; ++m_)                           \
      _Pragma("unroll") for (int n_ = 0; n_ < 2; ++n_)                         \
        _Pragma("unroll") for (int k_ = 0; k_ < 2; ++k_)                       \
          acc[QM][QN][m_][n_] = __builtin_amdgcn_mfma_f32_16x16x32_bf16(       \
              aF[m_][k_], BF[n_][k_], acc[QM][QN][m_][n_], 0, 0, 0);

// One K-tile: 4 quadrant phases. S2: stage tile T+2. D0/D1/D3: drains at the
// ends of Q0/Q1/Q3 (before the barrier releasing the next phase's reads).
#define TILE(T, S2, D0, D1, D3)                                                \
  {                                                                            \
    const int t_ = (T);                                                        \
    /* Q0: read A-h0 (8) + B-h0 (4); MFMA quad (0,0) */                        \
    _Pragma("unroll") for (int m_ = 0; m_ < 4; ++m_)                           \
      _Pragma("unroll") for (int k_ = 0; k_ < 2; ++k_)                         \
        aF[m_][k_] = rdA(t_, 0, m_, k_);                                       \
    _Pragma("unroll") for (int n_ = 0; n_ < 2; ++n_)                           \
      _Pragma("unroll") for (int k_ = 0; k_ < 2; ++k_)                         \
        bF0[n_][k_] = rdB(t_, 0, n_, k_);                                      \
    BAR(); PRIO1(); MFMA_Q(0, 0, bF0); PRIO0();                                \
    D0;                                                                        \
    BAR();                                                                     \
    /* Q1: read B-h1 (4); stage Ah0/Bh0(T+2); MFMA quad (0,1) */               \
    _Pragma("unroll") for (int n_ = 0; n_ < 2; ++n_)                           \
      _Pragma("unroll") for (int k_ = 0; k_ < 2; ++k_)                         \
        bF1[n_][k_] = rdB(t_, 1, n_, k_);                                      \
    if (S2) { stageA(t_ + 2, 0); stageB(t_ + 2, 0); }                          \
    BAR(); PRIO1(); MFMA_Q(0, 1, bF1); PRIO0();                                \
    D1;                                                                        \
    BAR();                                                                     \
    /* Q2: read A-h1 (8); stage Bh1(T+2); MFMA quad (1,1) */                   \
    _Pragma("unroll") for (int m_ = 0; m_ < 4; ++m_)                           \
      _Pragma("unroll") for (int k_ = 0; k_ < 2; ++k_)                         \
        aF[m_][k_] = rdA(t_, 1, m_, k_);                                       \
    if (S2) stageB(t_ + 2, 1);                                                 \
    BAR(); PRIO1(); MFMA_Q(1, 1, bF1); PRIO0(); BAR();                         \
    /* Q3: stage Ah1(T+2); MFMA quad (1,0) (aF=A-h1, bF0 kept from Q0) */      \
    if (S2) stageA(t_ + 2, 1);                                                 \
    BAR(); PRIO1(); MFMA_Q(1, 0, bF0); PRIO0();                                \
    D3;                                                                        \
    BAR();                                                                     \
  }

    // steady state: drains leave {later-issued} loads in flight.
    // Ledger (loads, 2 per stage): issues per tile: Q1:{Ah0,Bh0}(t+2)=4, Q2:Bh1(t+2)=2, Q3:Ah1(t+2)=2.
    //  D0 end-Q0(t): need Bh1(t)@Q2(t-2)  -> after it: Ah1(t)2 + tile(t+1)8        = vmcnt(10)
    //  D1 end-Q1(t): need Ah1(t)@Q3(t-2)  -> after it: tile(t+1)8 + {AB}h0(t+2)4   = vmcnt(12)
    //  D3 end-Q3(t): need {AB}h0(t+1)@Q1(t-1) -> after: Bh1,Ah1(t+1)4 + tile(t+2)8 = vmcnt(12)
    for (int t = 0; t < nt - 2; ++t)
        TILE(t, true,
             asm volatile("s_waitcnt vmcnt(10)" ::: "memory"),
             asm volatile("s_waitcnt vmcnt(12)" ::: "memory"),
             asm volatile("s_waitcnt vmcnt(12)" ::: "memory"));
    // t = nt-2: no tile-nt stages -> counts shrink
    TILE(nt - 2, false,
         asm volatile("s_waitcnt vmcnt(10)" ::: "memory"),
         asm volatile("s_waitcnt vmcnt(8)"  ::: "memory"),
         asm volatile("s_waitcnt vmcnt(4)"  ::: "memory"));
    // t = nt-1 (last): only tile-(nt-1) loads remain
    TILE(nt - 1, false,
         asm volatile("s_waitcnt vmcnt(2)" ::: "memory"),
         asm volatile("s_waitcnt vmcnt(0)" ::: "memory"),
         (void)0);

#undef TILE
#undef MFMA_Q
#undef BAR
#undef PRIO1
#undef PRIO0

    // epilogue: C/D layout col = lane&15, row = (lane>>4)*4 + reg
    const float bhv = (EPI == 1) ? bh_p[0] : 0.0f;
    #pragma unroll
    for (int qm = 0; qm < 2; ++qm)
        #pragma unroll
        for (int qn = 0; qn < 2; ++qn)
            #pragma unroll
            for (int m = 0; m < 4; ++m)
                #pragma unroll
                for (int n = 0; n < 2; ++n)
                    #pragma unroll
                    for (int r = 0; r < 4; ++r) {
                        const int row = row0 + qm * 128 + swr * 64 + m * 16 + fc * 4 + r;
                        const int col = col0 + qn * 128 + swc * 32 + n * 16 + fr;
                        float val = acc[qm][qn][m][n][r];
                        if (EPI == 1) {
                            val = fmaxf(val + bias[col], 0.0f);
                            const int b = row / 36;
                            val = val * qw[b * 2048 + col] + bhv;
                            ((short*)Cp)[(size_t)row * N + col] = f2bf(val);
                        } else {
                            ((float*)Cp)[(size_t)row * N + col] = val + bias[col];
                        }
                    }
}

// qw[b,h] = sum_q bf2f(q_[b*14+q, h]) * wh[q]
__global__ __launch_bounds__(256)
void qw_reduce(const short* __restrict__ q_, const float* __restrict__ wh,
               float* __restrict__ qw)
{
    const int idx = blockIdx.x * 256 + threadIdx.x;
    const int b = idx >> 11;
    const int h = idx & 2047;
    float s = 0.0f;
    #pragma unroll
    for (int qq = 0; qq < 14; ++qq)
        s += bf2f(q_[(size_t)(b * 14 + qq) * 2048 + h]) * wh[qq];
    qw[idx] = s;
}

extern "C" void kernel_launch(void* const* d_in, const int* in_sizes, int n_in,
                              void* d_out, int out_size, void* d_ws, size_t ws_size,
                              hipStream_t stream)
{
    const float* v  = (const float*)d_in[0];
    const float* q  = (const float*)d_in[1];
    const float* Wv = (const float*)d_in[2];
    const float* bv = (const float*)d_in[3];
    const float* Wq = (const float*)d_in[4];
    const float* bq = (const float*)d_in[5];
    const float* wh = (const float*)d_in[6];
    const float* bh = (const float*)d_in[7];
    const float* W2 = (const float*)d_in[8];
    const float* b2 = (const float*)d_in[9];
    float* out = (float*)d_out;

    char* ws = (char*)d_ws;
    short* vb     = (short*)(ws);                  // 4608*2048*2 = 18,874,368
    short* Wvb    = (short*)(ws + 18874368);       // 2048*2048*2 =  8,388,608
    short* W2b    = (short*)(ws + 27262976);       // 2048*2048*2 =  8,388,608
    short* qb     = (short*)(ws + 35651584);       // 1792*1024*2 =  3,670,016
    short* Wqb    = (short*)(ws + 39321600);       // 2048*1024*2 =  4,194,304
    short* q_ws   = (short*)(ws + 43515904);       // 1792*2048*2 =  7,340,032
    float* qw     = (float*)(ws + 50855936);       // 128*2048*4  =  1,048,576
    short* logits = (short*)(ws + 51904512);       // 4608*2048*2 = 18,874,368
    // total: 70,778,880 B

    auto cvt = [&](const float* src, short* dst, int n) {
        int blocks = (n / 8 + 255) / 256;
        if (blocks > 2048) blocks = 2048;
        cvt_bf16<<<blocks, 256, 0, stream>>>(src, dst, n);
    };

    cvt(q,  qb,  1792 * 1024);
    cvt(Wq, Wqb, 2048 * 1024);
    cvt(v,  vb,  4608 * 2048);
    cvt(Wv, Wvb, 2048 * 2048);
    cvt(W2, W2b, 2048 * 2048);

    // K1: q_ = relu(qb @ Wqb^T + bq)   M=1792, N=2048, K=1024  (128² kernel)
    gemm_bt128<<<dim3(1792 / 128, 2048 / 128), 256, 0, stream>>>(
        qb, Wqb, bq, q_ws, 1792, 2048, 1024);

    // K2: qw reduce
    qw_reduce<<<(128 * 2048) / 256, 256, 0, stream>>>(q_ws, wh, qw);

    // K3: logits = relu(vb @ Wvb^T + bv) * qw + bh   M=4608, N=2048, K=2048
    gemm256<1><<<dim3(4608 / 256, 2048 / 256), 512, 0, stream>>>(
        vb, Wvb, bv, qw, bh, logits, 4608, 2048, 2048);

    // K4: out = logits @ W2b^T + b2   M=4608, N=2048, K=2048
    gemm256<2><<<dim3(4608 / 256, 2048 / 256), 512, 0, stream>>>(
        logits, W2b, b2, nullptr, nullptr, out, 4608, 2048, 2048);
}

// Round 5
// 183.807 us; speedup vs baseline: 1.2940x; 1.0477x over previous
//
#include <hip/hip_runtime.h>
#include <hip/hip_bf16.h>

// BCNet fused pipeline, MI355X gfx950 — round 5.
// Back to the proven 128² skeleton, upgraded: triple-buffered LDS ring with
// counted vmcnt (T3/T4 minimum), involutive LDS slot-swizzle (T2, both-sides),
// XCD-aware block swizzle (T1), single merged cvt pass.
//   C0: convert v,q,Wv,Wq,W2 f32 -> bf16 (one kernel)
//   K1: q_[1792,2048]   = relu(qb @ Wqb^T + bq)
//   K2: qw[128,2048]    = sum_q q_[b*14+q,:] * wh[q]
//   K3: logits[4608,2048] = relu(vb @ Wvb^T + bv) * qw[b,:] + bh
//   K4: out[4608,2048]  = logits @ W2b^T + b2

typedef __attribute__((ext_vector_type(4))) float f32x4;
typedef __attribute__((ext_vector_type(8))) short short8;

__device__ __forceinline__ short f2bf(float f) {
    union { float f; unsigned u; } x; x.f = f;
    unsigned u = x.u;
    unsigned r = (u + 0x7FFFu + ((u >> 16) & 1u)) >> 16;   // RN-even
    return (short)(r & 0xFFFFu);
}
__device__ __forceinline__ float bf2f(short s) {
    union { unsigned u; float f; } x; x.u = ((unsigned)(unsigned short)s) << 16;
    return x.f;
}

__device__ __forceinline__ void gload_lds16(const short* g, short* l) {
    __builtin_amdgcn_global_load_lds(
        (const __attribute__((address_space(1))) unsigned int*)g,
        (__attribute__((address_space(3))) unsigned int*)l,
        16, 0, 0);
}

// ---------------- merged f32 -> bf16 conversion (5 tensors, 1 launch) ----------------
// chunk = 8 elems. chunk counts: v 1179648 | Wv 524288 | W2 524288 | q 229376 | Wq 262144
#define CV0 1179648
#define CV1 1703936   // +Wv
#define CV2 2228224   // +W2
#define CV3 2457600   // +q
#define CV4 2719744   // +Wq (total)
__global__ __launch_bounds__(256)
void cvt_all(const float* __restrict__ v,  short* __restrict__ vb,
             const float* __restrict__ Wv, short* __restrict__ Wvb,
             const float* __restrict__ W2, short* __restrict__ W2b,
             const float* __restrict__ q,  short* __restrict__ qb,
             const float* __restrict__ Wq, short* __restrict__ Wqb)
{
    const int stride = gridDim.x * 256;
    for (int c = blockIdx.x * 256 + threadIdx.x; c < CV4; c += stride) {
        const float* src; short* dst; int i;
        if      (c < CV0) { src = v;  dst = vb;  i = c * 8; }
        else if (c < CV1) { src = Wv; dst = Wvb; i = (c - CV0) * 8; }
        else if (c < CV2) { src = W2; dst = W2b; i = (c - CV1) * 8; }
        else if (c < CV3) { src = q;  dst = qb;  i = (c - CV2) * 8; }
        else              { src = Wq; dst = Wqb; i = (c - CV3) * 8; }
        f32x4 a = *(const f32x4*)&src[i];
        f32x4 b = *(const f32x4*)&src[i + 4];
        short8 s;
        #pragma unroll
        for (int j = 0; j < 4; ++j) { s[j] = f2bf(a[j]); s[4 + j] = f2bf(b[j]); }
        *(short8*)&dst[i] = s;
    }
}

// ---------------- 128² triple-buffered pipelined GEMM ----------------
// C[M,N] = A[M,K] * B[N,K]^T, A,B bf16 row-major.
// EPI: 0 = relu(acc+bias[n])                      -> bf16
//      1 = relu(acc+bias[n]) * qw[row/36, n] + bh -> bf16
//      2 = acc + bias[n]                          -> f32
// Ring of 3 LDS buffers (48 KB total -> 3 blocks/CU). Each iteration stages
// tile t+2 (4 gload_lds/wave), computes tile t, then drains with counted
// vmcnt(4): the drained loads (tile t+1) were issued a full iteration earlier.
// LDS slot-swizzle (involution): lds[row][slot] = global[row][slot ^ (row&3)],
// applied on the global SOURCE address (dest stays linear for gload_lds) and
// on the ds_read offset. Cuts the 16-lane stride-64B read conflict 8-way->4-way.
// Block mapping: XCD-aware: xcd = bid&7 owns ncols/8 full B-panels (L2-resident).
template<int EPI>
__global__ __launch_bounds__(256)
void gemm_tb(const short* __restrict__ Ab, const short* __restrict__ Bb,
             const float* __restrict__ bias, const float* __restrict__ qw,
             const float* __restrict__ bh_p, void* __restrict__ Cp,
             int nrows, int N, int K)
{
    __shared__ short ldsA[3][128 * 32];   // 24 KB
    __shared__ short ldsB[3][128 * 32];   // 24 KB

    const int tid    = threadIdx.x;
    const int lane   = tid & 63;
    const int wid    = tid >> 6;
    const int wr     = wid >> 1;
    const int wc     = wid & 1;
    const int lrow   = lane & 15;
    const int lchunk = lane >> 4;

    // XCD-aware bijective swizzle: requires ncols % 8 == 0 (here ncols = 16)
    const int ncols = N >> 7;
    const int cpx   = ncols >> 3;
    const int bid   = blockIdx.x;
    const int xcd   = bid & 7;
    const int idx   = bid >> 3;
    const int row0  = (idx % nrows) * 128;
    const int col0  = (xcd * cpx + idx / nrows) * 128;

    // staging: wave wid, issue i in {0,1}: covers tile rows wid*32+i*16+(lane>>2),
    // source col slot pre-swizzled: slot' = (lane&3) ^ ((lane>>2)&3)
    const int s_r = lane >> 2;
    const int s_c = ((lane & 3) ^ (s_r & 3)) * 8;

    f32x4 acc[4][4];
    #pragma unroll
    for (int i = 0; i < 4; ++i)
        #pragma unroll
        for (int j = 0; j < 4; ++j)
            acc[i][j] = (f32x4)0.0f;

    const int nk = K >> 5;   // BK = 32; assumes nk >= 3

    auto stage = [&](int kt, int b) {
        const int kc = kt * 32;
        #pragma unroll
        for (int i = 0; i < 2; ++i) {
            const int r = wid * 32 + i * 16 + s_r;
            gload_lds16(&Ab[(size_t)(row0 + r) * K + kc + s_c], &ldsA[b][wid * 1024 + i * 512]);
            gload_lds16(&Bb[(size_t)(col0 + r) * K + kc + s_c], &ldsB[b][wid * 1024 + i * 512]);
        }
    };

    auto compute = [&](int b) {
        short8 af[4], bfv[4];
        #pragma unroll
        for (int mi = 0; mi < 4; ++mi) {
            const int row = wr * 64 + mi * 16 + lrow;
            af[mi] = *(const short8*)&ldsA[b][row * 32 + ((lchunk ^ (row & 3)) * 8)];
        }
        #pragma unroll
        for (int ni = 0; ni < 4; ++ni) {
            const int row = wc * 64 + ni * 16 + lrow;
            bfv[ni] = *(const short8*)&ldsB[b][row * 32 + ((lchunk ^ (row & 3)) * 8)];
        }
        #pragma unroll
        for (int mi = 0; mi < 4; ++mi)
            #pragma unroll
            for (int ni = 0; ni < 4; ++ni)
                acc[mi][ni] = __builtin_amdgcn_mfma_f32_16x16x32_bf16(af[mi], bfv[ni], acc[mi][ni], 0, 0, 0);
    };

    // prologue: tiles 0,1 in flight (8 loads/wave); wait tile 0 (leave tile 1's 4)
    stage(0, 0);
    stage(1, 1);
    asm volatile("s_waitcnt vmcnt(4)" ::: "memory");
    __builtin_amdgcn_s_barrier();

    int b = 0;
    for (int t = 0; t < nk - 2; ++t) {
        const int b2 = (b + 2 >= 3) ? b - 1 : b + 2;
        stage(t + 2, b2);                                   // outstanding: t+1 (4) + t+2 (4)
        compute(b);
        asm volatile("s_waitcnt vmcnt(4)" ::: "memory");    // tile t+1 arrived
        __builtin_amdgcn_s_barrier();
        b = (b + 1 == 3) ? 0 : b + 1;
    }
    // t = nk-2: only tile nk-1's 4 loads outstanding
    compute(b);
    asm volatile("s_waitcnt vmcnt(0)" ::: "memory");
    __builtin_amdgcn_s_barrier();
    b = (b + 1 == 3) ? 0 : b + 1;
    // t = nk-1
    compute(b);

    // epilogue: C/D layout: col = lane&15, row = (lane>>4)*4 + reg
    const float bhv = (EPI == 1) ? bh_p[0] : 0.0f;
    #pragma unroll
    for (int mi = 0; mi < 4; ++mi) {
        #pragma unroll
        for (int ni = 0; ni < 4; ++ni) {
            #pragma unroll
            for (int r = 0; r < 4; ++r) {
                const int row = row0 + wr * 64 + mi * 16 + lchunk * 4 + r;
                const int col = col0 + wc * 64 + ni * 16 + lrow;
                float val = acc[mi][ni][r];
                if (EPI == 0) {
                    val = fmaxf(val + bias[col], 0.0f);
                    ((short*)Cp)[(size_t)row * N + col] = f2bf(val);
                } else if (EPI == 1) {
                    val = fmaxf(val + bias[col], 0.0f);
                    const int bb = row / 36;
                    val = val * qw[bb * 2048 + col] + bhv;
                    ((short*)Cp)[(size_t)row * N + col] = f2bf(val);
                } else {
                    ((float*)Cp)[(size_t)row * N + col] = val + bias[col];
                }
            }
        }
    }
}

// qw[b,h] = sum_q bf2f(q_[b*14+q, h]) * wh[q]
__global__ __launch_bounds__(256)
void qw_reduce(const short* __restrict__ q_, const float* __restrict__ wh,
               float* __restrict__ qw)
{
    const int idx = blockIdx.x * 256 + threadIdx.x;
    const int b = idx >> 11;
    const int h = idx & 2047;
    float s = 0.0f;
    #pragma unroll
    for (int qq = 0; qq < 14; ++qq)
        s += bf2f(q_[(size_t)(b * 14 + qq) * 2048 + h]) * wh[qq];
    qw[idx] = s;
}

extern "C" void kernel_launch(void* const* d_in, const int* in_sizes, int n_in,
                              void* d_out, int out_size, void* d_ws, size_t ws_size,
                              hipStream_t stream)
{
    const float* v  = (const float*)d_in[0];
    const float* q  = (const float*)d_in[1];
    const float* Wv = (const float*)d_in[2];
    const float* bv = (const float*)d_in[3];
    const float* Wq = (const float*)d_in[4];
    const float* bq = (const float*)d_in[5];
    const float* wh = (const float*)d_in[6];
    const float* bh = (const float*)d_in[7];
    const float* W2 = (const float*)d_in[8];
    const float* b2 = (const float*)d_in[9];
    float* out = (float*)d_out;

    char* ws = (char*)d_ws;
    short* vb     = (short*)(ws);                  // 4608*2048*2 = 18,874,368
    short* Wvb    = (short*)(ws + 18874368);       // 2048*2048*2 =  8,388,608
    short* W2b    = (short*)(ws + 27262976);       // 2048*2048*2 =  8,388,608
    short* qb     = (short*)(ws + 35651584);       // 1792*1024*2 =  3,670,016
    short* Wqb    = (short*)(ws + 39321600);       // 2048*1024*2 =  4,194,304
    short* q_ws   = (short*)(ws + 43515904);       // 1792*2048*2 =  7,340,032
    float* qw     = (float*)(ws + 50855936);       // 128*2048*4  =  1,048,576
    short* logits = (short*)(ws + 51904512);       // 4608*2048*2 = 18,874,368
    // total: 70,778,880 B

    // C0: all conversions in one launch
    cvt_all<<<2048, 256, 0, stream>>>(v, vb, Wv, Wvb, W2, W2b, q, qb, Wq, Wqb);

    // K1: q_ = relu(qb @ Wqb^T + bq)   M=1792 (nrows=14), N=2048, K=1024
    gemm_tb<0><<<14 * 16, 256, 0, stream>>>(qb, Wqb, bq, nullptr, nullptr,
                                            q_ws, 14, 2048, 1024);

    // K2: qw reduce
    qw_reduce<<<(128 * 2048) / 256, 256, 0, stream>>>(q_ws, wh, qw);

    // K3: logits = relu(vb @ Wvb^T + bv) * qw + bh   M=4608 (nrows=36), N=2048, K=2048
    gemm_tb<1><<<36 * 16, 256, 0, stream>>>(vb, Wvb, bv, qw, bh,
                                            logits, 36, 2048, 2048);

    // K4: out = logits @ W2b^T + b2   M=4608 (nrows=36), N=2048, K=2048
    gemm_tb<2><<<36 * 16, 256, 0, stream>>>(logits, W2b, b2, nullptr, nullptr,
                                            out, 36, 2048, 2048);
}

// Round 6
// 166.263 us; speedup vs baseline: 1.4305x; 1.1055x over previous
//
#include <hip/hip_runtime.h>
#include <hip/hip_bf16.h>

// BCNet fused pipeline, MI355X gfx950 — round 6.
// R2 skeleton (proven best) + BK=64 (halves barrier/drain events per FLOP)
// + derived both-sides XOR swizzle (row&7)<<4 for the 128B-row LDS tile.
// Default block order (blockIdx.x = row, fastest -> B-panel L2 reuse).
//   C0: convert v,q,Wv,Wq,W2 f32 -> bf16 (one kernel)
//   K1: q_[1792,2048]   = relu(qb @ Wqb^T + bq)
//   K2: qw[128,2048]    = sum_q q_[b*14+q,:] * wh[q]
//   K3: logits[4608,2048] = relu(vb @ Wvb^T + bv) * qw[b,:] + bh
//   K4: out[4608,2048]  = logits @ W2b^T + b2

typedef __attribute__((ext_vector_type(4))) float f32x4;
typedef __attribute__((ext_vector_type(8))) short short8;

__device__ __forceinline__ short f2bf(float f) {
    union { float f; unsigned u; } x; x.f = f;
    unsigned u = x.u;
    unsigned r = (u + 0x7FFFu + ((u >> 16) & 1u)) >> 16;   // RN-even
    return (short)(r & 0xFFFFu);
}
__device__ __forceinline__ float bf2f(short s) {
    union { unsigned u; float f; } x; x.u = ((unsigned)(unsigned short)s) << 16;
    return x.f;
}

__device__ __forceinline__ void gload_lds16(const short* g, short* l) {
    __builtin_amdgcn_global_load_lds(
        (const __attribute__((address_space(1))) unsigned int*)g,
        (__attribute__((address_space(3))) unsigned int*)l,
        16, 0, 0);
}

// ---------------- merged f32 -> bf16 conversion (5 tensors, 1 launch) ----------------
// chunk = 8 elems. chunk counts: v 1179648 | Wv 524288 | W2 524288 | q 229376 | Wq 262144
#define CV0 1179648
#define CV1 1703936   // +Wv
#define CV2 2228224   // +W2
#define CV3 2457600   // +q
#define CV4 2719744   // +Wq (total)
__global__ __launch_bounds__(256)
void cvt_all(const float* __restrict__ v,  short* __restrict__ vb,
             const float* __restrict__ Wv, short* __restrict__ Wvb,
             const float* __restrict__ W2, short* __restrict__ W2b,
             const float* __restrict__ q,  short* __restrict__ qb,
             const float* __restrict__ Wq, short* __restrict__ Wqb)
{
    const int stride = gridDim.x * 256;
    for (int c = blockIdx.x * 256 + threadIdx.x; c < CV4; c += stride) {
        const float* src; short* dst; int i;
        if      (c < CV0) { src = v;  dst = vb;  i = c * 8; }
        else if (c < CV1) { src = Wv; dst = Wvb; i = (c - CV0) * 8; }
        else if (c < CV2) { src = W2; dst = W2b; i = (c - CV1) * 8; }
        else if (c < CV3) { src = q;  dst = qb;  i = (c - CV2) * 8; }
        else              { src = Wq; dst = Wqb; i = (c - CV3) * 8; }
        f32x4 a = *(const f32x4*)&src[i];
        f32x4 b = *(const f32x4*)&src[i + 4];
        short8 s;
        #pragma unroll
        for (int j = 0; j < 4; ++j) { s[j] = f2bf(a[j]); s[4 + j] = f2bf(b[j]); }
        *(short8*)&dst[i] = s;
    }
}

// ---------------- 128² BK=64 GEMM ----------------
// C[M,N] = A[M,K] * B[N,K]^T, A,B bf16 row-major.
// EPI: 0 = relu(acc+bias[n])                      -> bf16
//      1 = relu(acc+bias[n]) * qw[row/36, n] + bh -> bf16
//      2 = acc + bias[n]                          -> f32
// BK=64: LDS tile [128][64] shorts (128B rows) -> canonical 16-way ds_read
// conflict if linear; fixed by involutive XOR swizzle byte ^= (row&7)<<4:
//   - gload_lds dest stays linear; global SOURCE col pre-swizzled
//     (col8 ^= lane>>3, where lane>>3 == row&7 for the staging mapping)
//   - ds_read offset applies the same XOR
// 16 read-lanes/k-chunk then spread over 8 bank-groups (2-way residual = free).
// Two __syncthreads per K-step (compiler-managed waitcnt), single LDS buffer,
// 32 KB -> ~4 blocks/CU limit by LDS; multi-block TLP hides the drain stall.
template<int EPI>
__global__ __launch_bounds__(256)
void gemm_bt(const short* __restrict__ Ab, const short* __restrict__ Bb,
             const float* __restrict__ bias, const float* __restrict__ qw,
             const float* __restrict__ bh_p, void* __restrict__ Cp,
             int M, int N, int K)
{
    __shared__ short ldsA[128 * 64];   // 16 KB
    __shared__ short ldsB[128 * 64];   // 16 KB

    const int tid    = threadIdx.x;
    const int lane   = tid & 63;
    const int wid    = tid >> 6;      // 0..3
    const int wr     = wid >> 1;      // 0..1
    const int wc     = wid & 1;       // 0..1
    const int lrow   = lane & 15;
    const int lchunk = lane >> 4;     // 0..3

    const int row0 = blockIdx.x * 128;
    const int col0 = blockIdx.y * 128;

    // staging geometry: wave w, issue i in 0..3 covers rows w*32+i*8+(lane>>3),
    // 8 shorts per lane. Source col pre-swizzled by the involution.
    const int s_r = lane >> 3;                       // 0..7 == row&7
    const int s_c = ((lane & 7) ^ s_r) * 8;          // pre-swizzled col (shorts)

    f32x4 acc[4][4];
    #pragma unroll
    for (int i = 0; i < 4; ++i)
        #pragma unroll
        for (int j = 0; j < 4; ++j)
            acc[i][j] = (f32x4)0.0f;

    const int nk = K >> 6;   // BK = 64

    auto stage = [&](int kt) {
        const int kc = kt * 64;
        #pragma unroll
        for (int i = 0; i < 4; ++i) {
            const int r = wid * 32 + i * 8 + s_r;
            gload_lds16(&Ab[(size_t)(row0 + r) * K + kc + s_c],
                        &ldsA[(wid * 32 + i * 8) * 64]);
            gload_lds16(&Bb[(size_t)(col0 + r) * K + kc + s_c],
                        &ldsB[(wid * 32 + i * 8) * 64]);
        }
    };

    auto compute = [&]() {
        short8 af[4][2], bfv[4][2];
        #pragma unroll
        for (int mi = 0; mi < 4; ++mi) {
            const int row = wr * 64 + mi * 16 + lrow;
            #pragma unroll
            for (int ks = 0; ks < 2; ++ks)
                af[mi][ks] = *(const short8*)((const char*)ldsA +
                    row * 128 + (((ks * 4 + lchunk) * 16) ^ ((row & 7) << 4)));
        }
        #pragma unroll
        for (int ni = 0; ni < 4; ++ni) {
            const int row = wc * 64 + ni * 16 + lrow;
            #pragma unroll
            for (int ks = 0; ks < 2; ++ks)
                bfv[ni][ks] = *(const short8*)((const char*)ldsB +
                    row * 128 + (((ks * 4 + lchunk) * 16) ^ ((row & 7) << 4)));
        }
        #pragma unroll
        for (int ks = 0; ks < 2; ++ks)
            #pragma unroll
            for (int mi = 0; mi < 4; ++mi)
                #pragma unroll
                for (int ni = 0; ni < 4; ++ni)
                    acc[mi][ni] = __builtin_amdgcn_mfma_f32_16x16x32_bf16(
                        af[mi][ks], bfv[ni][ks], acc[mi][ni], 0, 0, 0);
    };

    for (int kt = 0; kt < nk; ++kt) {
        if (kt) __syncthreads();      // readers done with the buffer
        stage(kt);
        __syncthreads();              // drain: staged tile visible
        compute();
    }

    // epilogue: C/D layout: col = lane&15, row = (lane>>4)*4 + reg
    const float bhv = (EPI == 1) ? bh_p[0] : 0.0f;
    #pragma unroll
    for (int mi = 0; mi < 4; ++mi) {
        #pragma unroll
        for (int ni = 0; ni < 4; ++ni) {
            #pragma unroll
            for (int r = 0; r < 4; ++r) {
                const int row = row0 + wr * 64 + mi * 16 + lchunk * 4 + r;
                const int col = col0 + wc * 64 + ni * 16 + lrow;
                float val = acc[mi][ni][r];
                if (EPI == 0) {
                    val = fmaxf(val + bias[col], 0.0f);
                    ((short*)Cp)[(size_t)row * N + col] = f2bf(val);
                } else if (EPI == 1) {
                    val = fmaxf(val + bias[col], 0.0f);
                    const int bb = row / 36;
                    val = val * qw[bb * 2048 + col] + bhv;
                    ((short*)Cp)[(size_t)row * N + col] = f2bf(val);
                } else {
                    ((float*)Cp)[(size_t)row * N + col] = val + bias[col];
                }
            }
        }
    }
}

// qw[b,h] = sum_q bf2f(q_[b*14+q, h]) * wh[q]
__global__ __launch_bounds__(256)
void qw_reduce(const short* __restrict__ q_, const float* __restrict__ wh,
               float* __restrict__ qw)
{
    const int idx = blockIdx.x * 256 + threadIdx.x;
    const int b = idx >> 11;
    const int h = idx & 2047;
    float s = 0.0f;
    #pragma unroll
    for (int qq = 0; qq < 14; ++qq)
        s += bf2f(q_[(size_t)(b * 14 + qq) * 2048 + h]) * wh[qq];
    qw[idx] = s;
}

extern "C" void kernel_launch(void* const* d_in, const int* in_sizes, int n_in,
                              void* d_out, int out_size, void* d_ws, size_t ws_size,
                              hipStream_t stream)
{
    const float* v  = (const float*)d_in[0];
    const float* q  = (const float*)d_in[1];
    const float* Wv = (const float*)d_in[2];
    const float* bv = (const float*)d_in[3];
    const float* Wq = (const float*)d_in[4];
    const float* bq = (const float*)d_in[5];
    const float* wh = (const float*)d_in[6];
    const float* bh = (const float*)d_in[7];
    const float* W2 = (const float*)d_in[8];
    const float* b2 = (const float*)d_in[9];
    float* out = (float*)d_out;

    char* ws = (char*)d_ws;
    short* vb     = (short*)(ws);                  // 4608*2048*2 = 18,874,368
    short* Wvb    = (short*)(ws + 18874368);       // 2048*2048*2 =  8,388,608
    short* W2b    = (short*)(ws + 27262976);       // 2048*2048*2 =  8,388,608
    short* qb     = (short*)(ws + 35651584);       // 1792*1024*2 =  3,670,016
    short* Wqb    = (short*)(ws + 39321600);       // 2048*1024*2 =  4,194,304
    short* q_ws   = (short*)(ws + 43515904);       // 1792*2048*2 =  7,340,032
    float* qw     = (float*)(ws + 50855936);       // 128*2048*4  =  1,048,576
    short* logits = (short*)(ws + 51904512);       // 4608*2048*2 = 18,874,368
    // total: 70,778,880 B

    // C0: all conversions in one launch
    cvt_all<<<2048, 256, 0, stream>>>(v, vb, Wv, Wvb, W2, W2b, q, qb, Wq, Wqb);

    // K1: q_ = relu(qb @ Wqb^T + bq)   M=1792, N=2048, K=1024
    gemm_bt<0><<<dim3(1792 / 128, 2048 / 128), 256, 0, stream>>>(
        qb, Wqb, bq, nullptr, nullptr, q_ws, 1792, 2048, 1024);

    // K2: qw reduce
    qw_reduce<<<(128 * 2048) / 256, 256, 0, stream>>>(q_ws, wh, qw);

    // K3: logits = relu(vb @ Wvb^T + bv) * qw + bh   M=4608, N=2048, K=2048
    gemm_bt<1><<<dim3(4608 / 128, 2048 / 128), 256, 0, stream>>>(
        vb, Wvb, bv, qw, bh, logits, 4608, 2048, 2048);

    // K4: out = logits @ W2b^T + b2   M=4608, N=2048, K=2048
    gemm_bt<2><<<dim3(4608 / 128, 2048 / 128), 256, 0, stream>>>(
        logits, W2b, b2, nullptr, nullptr, out, 4608, 2048, 2048);
}

// Round 7
// 158.401 us; speedup vs baseline: 1.5015x; 1.0496x over previous
//
#include <hip/hip_runtime.h>
#include <hip/hip_bf16.h>

// BCNet fused pipeline, MI355X gfx950 — round 7: true 8-phase 256² schedule.
//   C0: convert v,q,Wv,Wq,W2 f32 -> bf16 (one kernel)
//   K1: q_[1792,2048]   = relu(qb @ Wqb^T + bq)                  (128² BK=64)
//   K2: qw[128,2048]    = sum_q q_[b*14+q,:] * wh[q]
//   K3: logits[4608,2048] = relu(vb @ Wvb^T + bv) * qw[b,:] + bh (256² 8-phase)
//   K4: out[4608,2048]  = logits @ W2b^T + b2                    (256² 8-phase)
//
// 256² kernel: 8 waves (2M x 4N), per-wave C = 128x64, BK=64, 128 KiB LDS.
// Staging units (16 KB each, read in exactly 2 consecutive phases):
//   Aq0 = A rows {0-63}u{128-191} (mq=0 of both wr-blocks), Aq1 = complement
//   Bq0 = B rows {0-31}u{64-95}u{128-159}u{192-223} (nq=0), Bq1 = complement
// Quadrant order per K-tile: (0,0)(0,1)(1,1)(1,0):
//   Aq0 read ph1-2 | Bq1 ph2-3 | Aq1 ph3-4 | Bq0 ph1&4
// Stage schedule (iteration = tiles T0=2j,T1=2j+1, phases 1..8):
//   ph1:Aq1(T1) ph2:Bq0(T1) ph3:Aq0(T0+2) ph4:Bq1(T0+2)+vmcnt(4)
//   ph5:Aq1(T0+2) ph6:Bq0(T0+2) ph7:Aq0(T1+2) ph8:Bq1(T1+2)+vmcnt(4)
// Every drain retires loads issued 2-5 phases earlier; never vmcnt(0) mid-loop.

typedef __attribute__((ext_vector_type(4))) float f32x4;
typedef __attribute__((ext_vector_type(8))) short short8;

__device__ __forceinline__ short f2bf(float f) {
    union { float f; unsigned u; } x; x.f = f;
    unsigned u = x.u;
    unsigned r = (u + 0x7FFFu + ((u >> 16) & 1u)) >> 16;   // RN-even
    return (short)(r & 0xFFFFu);
}
__device__ __forceinline__ float bf2f(short s) {
    union { unsigned u; float f; } x; x.u = ((unsigned)(unsigned short)s) << 16;
    return x.f;
}

__device__ __forceinline__ void gload_lds16(const short* g, short* l) {
    __builtin_amdgcn_global_load_lds(
        (const __attribute__((address_space(1))) unsigned int*)g,
        (__attribute__((address_space(3))) unsigned int*)l,
        16, 0, 0);
}

// ---------------- merged f32 -> bf16 conversion (5 tensors, 1 launch) ----------------
#define CV0 1179648
#define CV1 1703936   // +Wv
#define CV2 2228224   // +W2
#define CV3 2457600   // +q
#define CV4 2719744   // +Wq (total)
__global__ __launch_bounds__(256)
void cvt_all(const float* __restrict__ v,  short* __restrict__ vb,
             const float* __restrict__ Wv, short* __restrict__ Wvb,
             const float* __restrict__ W2, short* __restrict__ W2b,
             const float* __restrict__ q,  short* __restrict__ qb,
             const float* __restrict__ Wq, short* __restrict__ Wqb)
{
    const int stride = gridDim.x * 256;
    for (int c = blockIdx.x * 256 + threadIdx.x; c < CV4; c += stride) {
        const float* src; short* dst; int i;
        if      (c < CV0) { src = v;  dst = vb;  i = c * 8; }
        else if (c < CV1) { src = Wv; dst = Wvb; i = (c - CV0) * 8; }
        else if (c < CV2) { src = W2; dst = W2b; i = (c - CV1) * 8; }
        else if (c < CV3) { src = q;  dst = qb;  i = (c - CV2) * 8; }
        else              { src = Wq; dst = Wqb; i = (c - CV3) * 8; }
        f32x4 a = *(const f32x4*)&src[i];
        f32x4 b = *(const f32x4*)&src[i + 4];
        short8 s;
        #pragma unroll
        for (int j = 0; j < 4; ++j) { s[j] = f2bf(a[j]); s[4 + j] = f2bf(b[j]); }
        *(short8*)&dst[i] = s;
    }
}

// ---------------- 128² BK=64 GEMM (K1) — R6, PMC-verified conflict-free ----------------
__global__ __launch_bounds__(256)
void gemm_bt128(const short* __restrict__ Ab, const short* __restrict__ Bb,
                const float* __restrict__ bias, void* __restrict__ Cp,
                int M, int N, int K)
{
    __shared__ short ldsA[128 * 64];
    __shared__ short ldsB[128 * 64];

    const int tid    = threadIdx.x;
    const int lane   = tid & 63;
    const int wid    = tid >> 6;
    const int wr     = wid >> 1;
    const int wc     = wid & 1;
    const int lrow   = lane & 15;
    const int lchunk = lane >> 4;

    const int row0 = blockIdx.x * 128;
    const int col0 = blockIdx.y * 128;

    const int s_r = lane >> 3;
    const int s_c = ((lane & 7) ^ s_r) * 8;

    f32x4 acc[4][4];
    #pragma unroll
    for (int i = 0; i < 4; ++i)
        #pragma unroll
        for (int j = 0; j < 4; ++j)
            acc[i][j] = (f32x4)0.0f;

    const int nk = K >> 6;

    for (int kt = 0; kt < nk; ++kt) {
        const int kc = kt * 64;
        if (kt) __syncthreads();
        #pragma unroll
        for (int i = 0; i < 4; ++i) {
            const int r = wid * 32 + i * 8 + s_r;
            gload_lds16(&Ab[(size_t)(row0 + r) * K + kc + s_c],
                        &ldsA[(wid * 32 + i * 8) * 64]);
            gload_lds16(&Bb[(size_t)(col0 + r) * K + kc + s_c],
                        &ldsB[(wid * 32 + i * 8) * 64]);
        }
        __syncthreads();

        short8 af[4][2], bfv[4][2];
        #pragma unroll
        for (int mi = 0; mi < 4; ++mi) {
            const int row = wr * 64 + mi * 16 + lrow;
            #pragma unroll
            for (int ks = 0; ks < 2; ++ks)
                af[mi][ks] = *(const short8*)((const char*)ldsA +
                    row * 128 + (((ks * 4 + lchunk) * 16) ^ ((row & 7) << 4)));
        }
        #pragma unroll
        for (int ni = 0; ni < 4; ++ni) {
            const int row = wc * 64 + ni * 16 + lrow;
            #pragma unroll
            for (int ks = 0; ks < 2; ++ks)
                bfv[ni][ks] = *(const short8*)((const char*)ldsB +
                    row * 128 + (((ks * 4 + lchunk) * 16) ^ ((row & 7) << 4)));
        }
        #pragma unroll
        for (int ks = 0; ks < 2; ++ks)
            #pragma unroll
            for (int mi = 0; mi < 4; ++mi)
                #pragma unroll
                for (int ni = 0; ni < 4; ++ni)
                    acc[mi][ni] = __builtin_amdgcn_mfma_f32_16x16x32_bf16(
                        af[mi][ks], bfv[ni][ks], acc[mi][ni], 0, 0, 0);
    }

    #pragma unroll
    for (int mi = 0; mi < 4; ++mi)
        #pragma unroll
        for (int ni = 0; ni < 4; ++ni)
            #pragma unroll
            for (int r = 0; r < 4; ++r) {
                const int row = row0 + wr * 64 + mi * 16 + lchunk * 4 + r;
                const int col = col0 + wc * 64 + ni * 16 + lrow;
                float val = fmaxf(acc[mi][ni][r] + bias[col], 0.0f);
                ((short*)Cp)[(size_t)row * N + col] = f2bf(val);
            }
}

// ---------------- 256² 8-phase pipelined GEMM (K3/K4) ----------------
// EPI: 1 = relu(acc+bias[n]) * qw[row/36, n] + bh -> bf16
//      2 = acc + bias[n]                          -> f32
// Grid: 1D, bid -> (row0 = (bid>>3)*256, col0 = (bid&7)*256); N must be 2048.
template<int EPI>
__global__ __launch_bounds__(512, 2)
void gemm256(const short* __restrict__ Ab, const short* __restrict__ Bb,
             const float* __restrict__ bias, const float* __restrict__ qw,
             const float* __restrict__ bh_p, void* __restrict__ Cp,
             int M, int N, int K)
{
    __shared__ short lds[2][4][128 * 64];   // [buf][Aq0,Aq1,Bq0,Bq1] = 128 KiB

    const int tid  = threadIdx.x;
    const int lane = tid & 63;
    const int w    = tid >> 6;     // 0..7
    const int wr   = w >> 2;       // 0..1
    const int wc   = w & 3;        // 0..3
    const int fr   = lane & 15;
    const int fc   = lane >> 4;

    const int bid  = blockIdx.x;
    const int row0 = (bid >> 3) * 256;
    const int col0 = (bid & 7) * 256;     // XCD x owns column x -> B panel L2-resident

    const int sl_s = lane >> 3;                    // 0..7
    const int sl_c = ((lane & 7) ^ sl_s) * 8;      // pre-swizzled source col (shorts)

    const int nt = K >> 6;         // even, >= 4

    f32x4 acc[8][4];
    #pragma unroll
    for (int i = 0; i < 8; ++i)
        #pragma unroll
        for (int j = 0; j < 4; ++j)
            acc[i][j] = (f32x4)0.0f;

    // stage unit Aq{q} of tile t: thread covers unit rows (w*2+i)*8 + (lane>>3)
    auto stageA = [&](int t, int q) {
        #pragma unroll
        for (int i = 0; i < 2; ++i) {
            const int g  = w * 2 + i;                  // 0..15: 8-row group in unit
            const int rl = g * 8 + sl_s;               // 0..127 unit row
            const int srow = row0 + (g >> 3) * 128 + q * 64 + (rl & 63);
            gload_lds16(&Ab[(size_t)srow * K + t * 64 + sl_c],
                        &lds[t & 1][q][g * 512]);
        }
    };
    auto stageB = [&](int t, int q) {
        #pragma unroll
        for (int i = 0; i < 2; ++i) {
            const int g  = w * 2 + i;
            const int rl = g * 8 + sl_s;
            const int srow = col0 + (rl >> 5) * 64 + q * 32 + (rl & 31);
            gload_lds16(&Bb[(size_t)srow * K + t * 64 + sl_c],
                        &lds[t & 1][2 + q][g * 512]);
        }
    };

    short8 aF[4][2], bF0[2][2], bF1[2][2];

#define READA(T, MQ)                                                            \
    _Pragma("unroll") for (int m_ = 0; m_ < 4; ++m_) {                          \
        const int rl_ = wr * 64 + m_ * 16 + fr;                                 \
        _Pragma("unroll") for (int k_ = 0; k_ < 2; ++k_)                        \
            aF[m_][k_] = *(const short8*)((const char*)&lds[(T) & 1][MQ][0]     \
                + rl_ * 128 + ((k_ * 64 + fc * 16) ^ ((rl_ & 7) << 4)));        \
    }
#define READB(T, NQ, DEST)                                                      \
    _Pragma("unroll") for (int n_ = 0; n_ < 2; ++n_) {                          \
        const int rl_ = wc * 32 + n_ * 16 + fr;                                 \
        _Pragma("unroll") for (int k_ = 0; k_ < 2; ++k_)                        \
            DEST[n_][k_] = *(const short8*)((const char*)&lds[(T) & 1][2 + (NQ)][0] \
                + rl_ * 128 + ((k_ * 64 + fc * 16) ^ ((rl_ & 7) << 4)));        \
    }
#define MFMAQ(MQ, NQ, BFR)                                                      \
    _Pragma("unroll") for (int m_ = 0; m_ < 4; ++m_)                            \
      _Pragma("unroll") for (int n_ = 0; n_ < 2; ++n_)                          \
        _Pragma("unroll") for (int k_ = 0; k_ < 2; ++k_)                        \
          acc[(MQ) * 4 + m_][(NQ) * 2 + n_] =                                   \
              __builtin_amdgcn_mfma_f32_16x16x32_bf16(                          \
                  aF[m_][k_], BFR[n_][k_], acc[(MQ) * 4 + m_][(NQ) * 2 + n_], 0, 0, 0);

#define BAR()   asm volatile("s_barrier" ::: "memory")
#define PRIO1() __builtin_amdgcn_s_setprio(1)
#define PRIO0() __builtin_amdgcn_s_setprio(0)
#define VM4()   asm volatile("s_waitcnt vmcnt(4)" ::: "memory")
#define VM0()   asm volatile("s_waitcnt vmcnt(0)" ::: "memory")

// One iteration = tiles (T0,T1), phases 1..8. ST1..ST8: staging; D4/D8: drains.
#define KITER(T0, T1, ST1, ST2, ST3, ST4, ST5, ST6, ST7, ST8, D4, D8)           \
  {                                                                             \
    /* ph1: Q(0,0) of T0 */                                                     \
    READA(T0, 0); READB(T0, 0, bF0); ST1;                                       \
    BAR(); PRIO1(); MFMAQ(0, 0, bF0); PRIO0(); BAR();                           \
    /* ph2: Q(0,1) */                                                           \
    READB(T0, 1, bF1); ST2;                                                     \
    BAR(); PRIO1(); MFMAQ(0, 1, bF1); PRIO0(); BAR();                           \
    /* ph3: Q(1,1) */                                                           \
    READA(T0, 1); ST3;                                                          \
    BAR(); PRIO1(); MFMAQ(1, 1, bF1); PRIO0(); BAR();                           \
    /* ph4: Q(1,0) — no ds_reads */                                             \
    ST4;                                                                        \
    BAR(); PRIO1(); MFMAQ(1, 0, bF0); PRIO0(); D4; BAR();                       \
    /* ph5: Q(0,0) of T1 */                                                     \
    READA(T1, 0); READB(T1, 0, bF0); ST5;                                       \
    BAR(); PRIO1(); MFMAQ(0, 0, bF0); PRIO0(); BAR();                           \
    /* ph6: Q(0,1) */                                                           \
    READB(T1, 1, bF1); ST6;                                                     \
    BAR(); PRIO1(); MFMAQ(0, 1, bF1); PRIO0(); BAR();                           \
    /* ph7: Q(1,1) */                                                           \
    READA(T1, 1); ST7;                                                          \
    BAR(); PRIO1(); MFMAQ(1, 1, bF1); PRIO0(); BAR();                           \
    /* ph8: Q(1,0) */                                                           \
    ST8;                                                                        \
    BAR(); PRIO1(); MFMAQ(1, 0, bF0); PRIO0(); D8; BAR();                       \
  }

    // prologue: T0 fully + Aq0(T1), Bq1(T1); drain to T0-complete (leave 2 stages)
    stageA(0, 0); stageB(0, 0); stageB(0, 1); stageA(0, 1);
    stageA(1, 0); stageB(1, 1);
    VM4();
    BAR();

    const int niter = (nt >> 1) - 1;
    for (int j = 0; j < niter; ++j) {
        const int t0 = 2 * j, t1 = 2 * j + 1;
        KITER(t0, t1,
              stageA(t1, 1),     stageB(t1, 0),
              stageA(t0 + 2, 0), stageB(t0 + 2, 1),
              stageA(t0 + 2, 1), stageB(t0 + 2, 0),
              stageA(t1 + 2, 0), stageB(t1 + 2, 1),
              VM4(), VM4());
    }
    // peeled last iteration: only T1's remaining units; drain fully at ph4
    {
        const int t0 = nt - 2, t1 = nt - 1;
        KITER(t0, t1,
              stageA(t1, 1), stageB(t1, 0),
              (void)0, (void)0, (void)0, (void)0, (void)0, (void)0,
              VM0(), (void)0);
    }

#undef KITER
#undef READA
#undef READB
#undef MFMAQ
#undef BAR
#undef PRIO1
#undef PRIO0
#undef VM4
#undef VM0

    // epilogue: C/D layout col = lane&15, row = (lane>>4)*4 + reg
    const float bhv = (EPI == 1) ? bh_p[0] : 0.0f;
    #pragma unroll
    for (int m = 0; m < 8; ++m) {
        #pragma unroll
        for (int n = 0; n < 4; ++n) {
            #pragma unroll
            for (int r = 0; r < 4; ++r) {
                const int row = row0 + wr * 128 + m * 16 + fc * 4 + r;
                const int col = col0 + wc * 64 + n * 16 + fr;
                float val = acc[m][n][r];
                if (EPI == 1) {
                    val = fmaxf(val + bias[col], 0.0f);
                    const int b = row / 36;
                    val = val * qw[b * 2048 + col] + bhv;
                    ((short*)Cp)[(size_t)row * N + col] = f2bf(val);
                } else {
                    ((float*)Cp)[(size_t)row * N + col] = val + bias[col];
                }
            }
        }
    }
}

// qw[b,h] = sum_q bf2f(q_[b*14+q, h]) * wh[q]
__global__ __launch_bounds__(256)
void qw_reduce(const short* __restrict__ q_, const float* __restrict__ wh,
               float* __restrict__ qw)
{
    const int idx = blockIdx.x * 256 + threadIdx.x;
    const int b = idx >> 11;
    const int h = idx & 2047;
    float s = 0.0f;
    #pragma unroll
    for (int qq = 0; qq < 14; ++qq)
        s += bf2f(q_[(size_t)(b * 14 + qq) * 2048 + h]) * wh[qq];
    qw[idx] = s;
}

extern "C" void kernel_launch(void* const* d_in, const int* in_sizes, int n_in,
                              void* d_out, int out_size, void* d_ws, size_t ws_size,
                              hipStream_t stream)
{
    const float* v  = (const float*)d_in[0];
    const float* q  = (const float*)d_in[1];
    const float* Wv = (const float*)d_in[2];
    const float* bv = (const float*)d_in[3];
    const float* Wq = (const float*)d_in[4];
    const float* bq = (const float*)d_in[5];
    const float* wh = (const float*)d_in[6];
    const float* bh = (const float*)d_in[7];
    const float* W2 = (const float*)d_in[8];
    const float* b2 = (const float*)d_in[9];
    float* out = (float*)d_out;

    char* ws = (char*)d_ws;
    short* vb     = (short*)(ws);                  // 4608*2048*2 = 18,874,368
    short* Wvb    = (short*)(ws + 18874368);       // 2048*2048*2 =  8,388,608
    short* W2b    = (short*)(ws + 27262976);       // 2048*2048*2 =  8,388,608
    short* qb     = (short*)(ws + 35651584);       // 1792*1024*2 =  3,670,016
    short* Wqb    = (short*)(ws + 39321600);       // 2048*1024*2 =  4,194,304
    short* q_ws   = (short*)(ws + 43515904);       // 1792*2048*2 =  7,340,032
    float* qw     = (float*)(ws + 50855936);       // 128*2048*4  =  1,048,576
    short* logits = (short*)(ws + 51904512);       // 4608*2048*2 = 18,874,368
    // total: 70,778,880 B

    // C0: all conversions in one launch
    cvt_all<<<2048, 256, 0, stream>>>(v, vb, Wv, Wvb, W2, W2b, q, qb, Wq, Wqb);

    // K1: q_ = relu(qb @ Wqb^T + bq)   M=1792, N=2048, K=1024
    gemm_bt128<<<dim3(1792 / 128, 2048 / 128), 256, 0, stream>>>(
        qb, Wqb, bq, q_ws, 1792, 2048, 1024);

    // K2: qw reduce
    qw_reduce<<<(128 * 2048) / 256, 256, 0, stream>>>(q_ws, wh, qw);

    // K3: logits = relu(vb @ Wvb^T + bv) * qw + bh   M=4608, N=2048, K=2048
    gemm256<1><<<(4608 / 256) * (2048 / 256), 512, 0, stream>>>(
        vb, Wvb, bv, qw, bh, logits, 4608, 2048, 2048);

    // K4: out = logits @ W2b^T + b2   M=4608, N=2048, K=2048
    gemm256<2><<<(4608 / 256) * (2048 / 256), 512, 0, stream>>>(
        logits, W2b, b2, nullptr, nullptr, out, 4608, 2048, 2048);
}

// Round 8
// 147.467 us; speedup vs baseline: 1.6129x; 1.0741x over previous
//
#include <hip/hip_runtime.h>
#include <hip/hip_bf16.h>

// BCNet fused pipeline, MI355X gfx950 — round 8: 8-phase 256² with rotated
// phases (frag reads after MFMA -> same-wave LDS/MFMA overlap), ONE barrier
// per phase (audited), row-fastest grid (L2 reuse as in R2).
//   C0: convert v,q,Wv,Wq,W2 f32 -> bf16 (one kernel)
//   K1: q_[1792,2048]   = relu(qb @ Wqb^T + bq)                  (128² BK=64)
//   K2: qw[128,2048]    = sum_q q_[b*14+q,:] * wh[q]
//   K3: logits[4608,2048] = relu(vb @ Wvb^T + bv) * qw[b,:] + bh (256² 8-phase)
//   K4: out[4608,2048]  = logits @ W2b^T + b2                    (256² 8-phase)

typedef __attribute__((ext_vector_type(4))) float f32x4;
typedef __attribute__((ext_vector_type(8))) short short8;

__device__ __forceinline__ short f2bf(float f) {
    union { float f; unsigned u; } x; x.f = f;
    unsigned u = x.u;
    unsigned r = (u + 0x7FFFu + ((u >> 16) & 1u)) >> 16;   // RN-even
    return (short)(r & 0xFFFFu);
}
__device__ __forceinline__ float bf2f(short s) {
    union { unsigned u; float f; } x; x.u = ((unsigned)(unsigned short)s) << 16;
    return x.f;
}

__device__ __forceinline__ void gload_lds16(const short* g, short* l) {
    __builtin_amdgcn_global_load_lds(
        (const __attribute__((address_space(1))) unsigned int*)g,
        (__attribute__((address_space(3))) unsigned int*)l,
        16, 0, 0);
}

// ---------------- merged f32 -> bf16 conversion (5 tensors, 1 launch) ----------------
#define CV0 1179648
#define CV1 1703936   // +Wv
#define CV2 2228224   // +W2
#define CV3 2457600   // +q
#define CV4 2719744   // +Wq (total)
__global__ __launch_bounds__(256)
void cvt_all(const float* __restrict__ v,  short* __restrict__ vb,
             const float* __restrict__ Wv, short* __restrict__ Wvb,
             const float* __restrict__ W2, short* __restrict__ W2b,
             const float* __restrict__ q,  short* __restrict__ qb,
             const float* __restrict__ Wq, short* __restrict__ Wqb)
{
    const int stride = gridDim.x * 256;
    for (int c = blockIdx.x * 256 + threadIdx.x; c < CV4; c += stride) {
        const float* src; short* dst; int i;
        if      (c < CV0) { src = v;  dst = vb;  i = c * 8; }
        else if (c < CV1) { src = Wv; dst = Wvb; i = (c - CV0) * 8; }
        else if (c < CV2) { src = W2; dst = W2b; i = (c - CV1) * 8; }
        else if (c < CV3) { src = q;  dst = qb;  i = (c - CV2) * 8; }
        else              { src = Wq; dst = Wqb; i = (c - CV3) * 8; }
        f32x4 a = *(const f32x4*)&src[i];
        f32x4 b = *(const f32x4*)&src[i + 4];
        short8 s;
        #pragma unroll
        for (int j = 0; j < 4; ++j) { s[j] = f2bf(a[j]); s[4 + j] = f2bf(b[j]); }
        *(short8*)&dst[i] = s;
    }
}

// ---------------- 128² BK=64 GEMM (K1) ----------------
__global__ __launch_bounds__(256)
void gemm_bt128(const short* __restrict__ Ab, const short* __restrict__ Bb,
                const float* __restrict__ bias, void* __restrict__ Cp,
                int M, int N, int K)
{
    __shared__ short ldsA[128 * 64];
    __shared__ short ldsB[128 * 64];

    const int tid    = threadIdx.x;
    const int lane   = tid & 63;
    const int wid    = tid >> 6;
    const int wr     = wid >> 1;
    const int wc     = wid & 1;
    const int lrow   = lane & 15;
    const int lchunk = lane >> 4;

    const int row0 = blockIdx.x * 128;
    const int col0 = blockIdx.y * 128;

    const int s_r = lane >> 3;
    const int s_c = ((lane & 7) ^ s_r) * 8;

    f32x4 acc[4][4];
    #pragma unroll
    for (int i = 0; i < 4; ++i)
        #pragma unroll
        for (int j = 0; j < 4; ++j)
            acc[i][j] = (f32x4)0.0f;

    const int nk = K >> 6;

    for (int kt = 0; kt < nk; ++kt) {
        const int kc = kt * 64;
        if (kt) __syncthreads();
        #pragma unroll
        for (int i = 0; i < 4; ++i) {
            const int r = wid * 32 + i * 8 + s_r;
            gload_lds16(&Ab[(size_t)(row0 + r) * K + kc + s_c],
                        &ldsA[(wid * 32 + i * 8) * 64]);
            gload_lds16(&Bb[(size_t)(col0 + r) * K + kc + s_c],
                        &ldsB[(wid * 32 + i * 8) * 64]);
        }
        __syncthreads();

        short8 af[4][2], bfv[4][2];
        #pragma unroll
        for (int mi = 0; mi < 4; ++mi) {
            const int row = wr * 64 + mi * 16 + lrow;
            #pragma unroll
            for (int ks = 0; ks < 2; ++ks)
                af[mi][ks] = *(const short8*)((const char*)ldsA +
                    row * 128 + (((ks * 4 + lchunk) * 16) ^ ((row & 7) << 4)));
        }
        #pragma unroll
        for (int ni = 0; ni < 4; ++ni) {
            const int row = wc * 64 + ni * 16 + lrow;
            #pragma unroll
            for (int ks = 0; ks < 2; ++ks)
                bfv[ni][ks] = *(const short8*)((const char*)ldsB +
                    row * 128 + (((ks * 4 + lchunk) * 16) ^ ((row & 7) << 4)));
        }
        #pragma unroll
        for (int ks = 0; ks < 2; ++ks)
            #pragma unroll
            for (int mi = 0; mi < 4; ++mi)
                #pragma unroll
                for (int ni = 0; ni < 4; ++ni)
                    acc[mi][ni] = __builtin_amdgcn_mfma_f32_16x16x32_bf16(
                        af[mi][ks], bfv[ni][ks], acc[mi][ni], 0, 0, 0);
    }

    #pragma unroll
    for (int mi = 0; mi < 4; ++mi)
        #pragma unroll
        for (int ni = 0; ni < 4; ++ni)
            #pragma unroll
            for (int r = 0; r < 4; ++r) {
                const int row = row0 + wr * 64 + mi * 16 + lchunk * 4 + r;
                const int col = col0 + wc * 64 + ni * 16 + lrow;
                float val = fmaxf(acc[mi][ni][r] + bias[col], 0.0f);
                ((short*)Cp)[(size_t)row * N + col] = f2bf(val);
            }
}

// ---------------- 256² 8-phase pipelined GEMM, rotated phases (K3/K4) ----------------
// EPI: 1 = relu(acc+bias[n]) * qw[row/36, n] + bh -> bf16
//      2 = acc + bias[n]                          -> f32
// Units: Aq{0,1} (rows mq*64.. of both 128-blocks), Bq{0,1} (rows nq-quads).
// Phase p: [top reads only at ph1/ph5] MFMA; tail-read next phase's frags;
// stage; [drain at ph4/ph8]; ONE barrier.
// Frag choreography: A0,A1,B0,B1 — see per-phase comments.
template<int EPI>
__global__ __launch_bounds__(512, 2)
void gemm256(const short* __restrict__ Ab, const short* __restrict__ Bb,
             const float* __restrict__ bias, const float* __restrict__ qw,
             const float* __restrict__ bh_p, void* __restrict__ Cp,
             int M, int N, int K)
{
    __shared__ short lds[2][4][128 * 64];   // [buf][Aq0,Aq1,Bq0,Bq1] = 128 KiB

    const int tid  = threadIdx.x;
    const int lane = tid & 63;
    const int w    = tid >> 6;     // 0..7
    const int wr   = w >> 2;       // 0..1
    const int wc   = w & 3;        // 0..3
    const int fr   = lane & 15;
    const int fc   = lane >> 4;

    const int row0 = blockIdx.x * 256;   // row-fastest grid: consecutive bids share col panel
    const int col0 = blockIdx.y * 256;

    const int sl_s = lane >> 3;                    // 0..7
    const int sl_c = ((lane & 7) ^ sl_s) * 8;      // pre-swizzled source col (shorts)

    const int nt = K >> 6;         // even, >= 4

    f32x4 acc[8][4];
    #pragma unroll
    for (int i = 0; i < 8; ++i)
        #pragma unroll
        for (int j = 0; j < 4; ++j)
            acc[i][j] = (f32x4)0.0f;

    auto stageA = [&](int t, int q) {
        #pragma unroll
        for (int i = 0; i < 2; ++i) {
            const int g  = w * 2 + i;                  // 0..15
            const int rl = g * 8 + sl_s;               // 0..127 unit row
            const int srow = row0 + (g >> 3) * 128 + q * 64 + (rl & 63);
            gload_lds16(&Ab[(size_t)srow * K + t * 64 + sl_c],
                        &lds[t & 1][q][g * 512]);
        }
    };
    auto stageB = [&](int t, int q) {
        #pragma unroll
        for (int i = 0; i < 2; ++i) {
            const int g  = w * 2 + i;
            const int rl = g * 8 + sl_s;
            const int srow = col0 + (rl >> 5) * 64 + q * 32 + (rl & 31);
            gload_lds16(&Bb[(size_t)srow * K + t * 64 + sl_c],
                        &lds[t & 1][2 + q][g * 512]);
        }
    };

    short8 A0[4][2], A1[4][2], B0[2][2], B1[2][2];

#define READA(T, MQ, DST)                                                       \
    _Pragma("unroll") for (int m_ = 0; m_ < 4; ++m_) {                          \
        const int rl_ = wr * 64 + m_ * 16 + fr;                                 \
        _Pragma("unroll") for (int k_ = 0; k_ < 2; ++k_)                        \
            DST[m_][k_] = *(const short8*)((const char*)&lds[(T) & 1][MQ][0]    \
                + rl_ * 128 + ((k_ * 64 + fc * 16) ^ ((rl_ & 7) << 4)));        \
    }
#define READB(T, NQ, DST)                                                       \
    _Pragma("unroll") for (int n_ = 0; n_ < 2; ++n_) {                          \
        const int rl_ = wc * 32 + n_ * 16 + fr;                                 \
        _Pragma("unroll") for (int k_ = 0; k_ < 2; ++k_)                        \
            DST[n_][k_] = *(const short8*)((const char*)&lds[(T) & 1][2 + (NQ)][0] \
                + rl_ * 128 + ((k_ * 64 + fc * 16) ^ ((rl_ & 7) << 4)));        \
    }
#define MFMAQ(MQ, NQ, ASET, BSET)                                               \
    _Pragma("unroll") for (int m_ = 0; m_ < 4; ++m_)                            \
      _Pragma("unroll") for (int n_ = 0; n_ < 2; ++n_)                          \
        _Pragma("unroll") for (int k_ = 0; k_ < 2; ++k_)                        \
          acc[(MQ) * 4 + m_][(NQ) * 2 + n_] =                                   \
              __builtin_amdgcn_mfma_f32_16x16x32_bf16(                          \
                  ASET[m_][k_], BSET[n_][k_], acc[(MQ) * 4 + m_][(NQ) * 2 + n_], 0, 0, 0);

#define BAR()   asm volatile("s_barrier" ::: "memory")
#define PRIO1() __builtin_amdgcn_s_setprio(1)
#define PRIO0() __builtin_amdgcn_s_setprio(0)
#define VM4()   asm volatile("s_waitcnt vmcnt(4)" ::: "memory")
#define VM0()   asm volatile("s_waitcnt vmcnt(0)" ::: "memory")

// One iteration = tiles (T0,T1), 8 phases, ONE barrier each.
// ST slots: ST1:Aq1(T1) ST2:Bq0(T1) ST3:Aq0(T0+2) ST4:Bq1(T0+2)
//           ST5:Aq1(T0+2) ST6:Bq0(T0+2) ST7:Aq0(T1+2) ST8:Bq1(T1+2)
// Drains: D4 after ST4 (T1 complete), D8 after ST8 (T0+2 complete).
#define KITER(T0, T1, ST1, ST2, ST3, ST4, ST5, ST6, ST7, ST8, D4, D8)           \
  {                                                                             \
    /* ph1: top-read A0=Aq0(T0), B0=Bq0(T0); MFMA(0,0); tail B1=Bq1(T0) */      \
    READA(T0, 0, A0); READB(T0, 0, B0);                                         \
    PRIO1(); MFMAQ(0, 0, A0, B0); PRIO0();                                      \
    READB(T0, 1, B1); ST1; BAR();                                               \
    /* ph2: MFMA(0,1)=A0*B1; tail A1=Aq1(T0) */                                 \
    PRIO1(); MFMAQ(0, 1, A0, B1); PRIO0();                                      \
    READA(T0, 1, A1); ST2; BAR();                                               \
    /* ph3: MFMA(1,1)=A1*B1 */                                                  \
    PRIO1(); MFMAQ(1, 1, A1, B1); PRIO0();                                      \
    ST3; BAR();                                                                 \
    /* ph4: MFMA(1,0)=A1*B0; drain T1 */                                        \
    PRIO1(); MFMAQ(1, 0, A1, B0); PRIO0();                                      \
    ST4; D4; BAR();                                                             \
    /* ph5: top-read A0=Aq0(T1), B0=Bq0(T1); MFMA(0,0); tail B1=Bq1(T1) */      \
    READA(T1, 0, A0); READB(T1, 0, B0);                                         \
    PRIO1(); MFMAQ(0, 0, A0, B0); PRIO0();                                      \
    READB(T1, 1, B1); ST5; BAR();                                               \
    /* ph6: MFMA(0,1); tail A1=Aq1(T1) */                                       \
    PRIO1(); MFMAQ(0, 1, A0, B1); PRIO0();                                      \
    READA(T1, 1, A1); ST6; BAR();                                               \
    /* ph7: MFMA(1,1) */                                                        \
    PRIO1(); MFMAQ(1, 1, A1, B1); PRIO0();                                      \
    ST7; BAR();                                                                 \
    /* ph8: MFMA(1,0); drain T0+2 */                                            \
    PRIO1(); MFMAQ(1, 0, A1, B0); PRIO0();                                      \
    ST8; D8; BAR();                                                             \
  }

    // prologue: T0 fully + Aq0(T1) + Bq1(T1); drain to T0-complete
    stageA(0, 0); stageB(0, 0); stageB(0, 1); stageA(0, 1);
    stageA(1, 0); stageB(1, 1);
    VM4();
    BAR();

    const int niter = (nt >> 1) - 1;
    for (int j = 0; j < niter; ++j) {
        const int t0 = 2 * j, t1 = 2 * j + 1;
        KITER(t0, t1,
              stageA(t1, 1),     stageB(t1, 0),
              stageA(t0 + 2, 0), stageB(t0 + 2, 1),
              stageA(t0 + 2, 1), stageB(t0 + 2, 0),
              stageA(t1 + 2, 0), stageB(t1 + 2, 1),
              VM4(), VM4());
    }
    // tail iteration: T0=nt-2, T1=nt-1; only T1's remaining units staged
    {
        const int t0 = nt - 2, t1 = nt - 1;
        KITER(t0, t1,
              stageA(t1, 1), stageB(t1, 0),
              (void)0, (void)0, (void)0, (void)0, (void)0, (void)0,
              VM0(), (void)0);
    }

#undef KITER
#undef READA
#undef READB
#undef MFMAQ
#undef BAR
#undef PRIO1
#undef PRIO0
#undef VM4
#undef VM0

    // epilogue: C/D layout col = lane&15, row = (lane>>4)*4 + reg
    const float bhv = (EPI == 1) ? bh_p[0] : 0.0f;
    #pragma unroll
    for (int m = 0; m < 8; ++m) {
        #pragma unroll
        for (int n = 0; n < 4; ++n) {
            #pragma unroll
            for (int r = 0; r < 4; ++r) {
                const int row = row0 + wr * 128 + m * 16 + fc * 4 + r;
                const int col = col0 + wc * 64 + n * 16 + fr;
                float val = acc[m][n][r];
                if (EPI == 1) {
                    val = fmaxf(val + bias[col], 0.0f);
                    const int b = row / 36;
                    val = val * qw[b * 2048 + col] + bhv;
                    ((short*)Cp)[(size_t)row * N + col] = f2bf(val);
                } else {
                    ((float*)Cp)[(size_t)row * N + col] = val + bias[col];
                }
            }
        }
    }
}

// qw[b,h] = sum_q bf2f(q_[b*14+q, h]) * wh[q]
__global__ __launch_bounds__(256)
void qw_reduce(const short* __restrict__ q_, const float* __restrict__ wh,
               float* __restrict__ qw)
{
    const int idx = blockIdx.x * 256 + threadIdx.x;
    const int b = idx >> 11;
    const int h = idx & 2047;
    float s = 0.0f;
    #pragma unroll
    for (int qq = 0; qq < 14; ++qq)
        s += bf2f(q_[(size_t)(b * 14 + qq) * 2048 + h]) * wh[qq];
    qw[idx] = s;
}

extern "C" void kernel_launch(void* const* d_in, const int* in_sizes, int n_in,
                              void* d_out, int out_size, void* d_ws, size_t ws_size,
                              hipStream_t stream)
{
    const float* v  = (const float*)d_in[0];
    const float* q  = (const float*)d_in[1];
    const float* Wv = (const float*)d_in[2];
    const float* bv = (const float*)d_in[3];
    const float* Wq = (const float*)d_in[4];
    const float* bq = (const float*)d_in[5];
    const float* wh = (const float*)d_in[6];
    const float* bh = (const float*)d_in[7];
    const float* W2 = (const float*)d_in[8];
    const float* b2 = (const float*)d_in[9];
    float* out = (float*)d_out;

    char* ws = (char*)d_ws;
    short* vb     = (short*)(ws);                  // 4608*2048*2 = 18,874,368
    short* Wvb    = (short*)(ws + 18874368);       // 2048*2048*2 =  8,388,608
    short* W2b    = (short*)(ws + 27262976);       // 2048*2048*2 =  8,388,608
    short* qb     = (short*)(ws + 35651584);       // 1792*1024*2 =  3,670,016
    short* Wqb    = (short*)(ws + 39321600);       // 2048*1024*2 =  4,194,304
    short* q_ws   = (short*)(ws + 43515904);       // 1792*2048*2 =  7,340,032
    float* qw     = (float*)(ws + 50855936);       // 128*2048*4  =  1,048,576
    short* logits = (short*)(ws + 51904512);       // 4608*2048*2 = 18,874,368
    // total: 70,778,880 B

    // C0: all conversions in one launch
    cvt_all<<<2048, 256, 0, stream>>>(v, vb, Wv, Wvb, W2, W2b, q, qb, Wq, Wqb);

    // K1: q_ = relu(qb @ Wqb^T + bq)   M=1792, N=2048, K=1024
    gemm_bt128<<<dim3(1792 / 128, 2048 / 128), 256, 0, stream>>>(
        qb, Wqb, bq, q_ws, 1792, 2048, 1024);

    // K2: qw reduce
    qw_reduce<<<(128 * 2048) / 256, 256, 0, stream>>>(q_ws, wh, qw);

    // K3: logits = relu(vb @ Wvb^T + bv) * qw + bh   M=4608, N=2048, K=2048
    gemm256<1><<<dim3(4608 / 256, 2048 / 256), 512, 0, stream>>>(
        vb, Wvb, bv, qw, bh, logits, 4608, 2048, 2048);

    // K4: out = logits @ W2b^T + b2   M=4608, N=2048, K=2048
    gemm256<2><<<dim3(4608 / 256, 2048 / 256), 512, 0, stream>>>(
        logits, W2b, b2, nullptr, nullptr, out, 4608, 2048, 2048);
}